// Round 6
// baseline (20484.262 us; speedup 1.0000x reference)
//
#include <hip/hip_runtime.h>
#include <hip/hip_bf16.h>
#include <hip/hip_cooperative_groups.h>

namespace cg = cooperative_groups;

typedef __attribute__((ext_vector_type(8))) short short8v;   // 8 bf16 = 16 B
typedef __attribute__((ext_vector_type(4))) float f32x4;

union SV { short8v v; unsigned short u[8]; };
union FU { float f; unsigned u; };

// Truncation split: x ~= hi + lo, residual <= 2^-16 |x|.
__device__ __forceinline__ void split2(float x, unsigned short& hi, unsigned short& lo) {
    FU a; a.f = x;
    hi = (unsigned short)(a.u >> 16);
    FU h; h.u = a.u & 0xffff0000u;
    FU r; r.f = x - h.f;              // exact
    lo = (unsigned short)(r.u >> 16);
}
__device__ __forceinline__ void split8(const float4 a0, const float4 a1, SV& h, SV& l) {
    split2(a0.x, h.u[0], l.u[0]); split2(a0.y, h.u[1], l.u[1]);
    split2(a0.z, h.u[2], l.u[2]); split2(a0.w, h.u[3], l.u[3]);
    split2(a1.x, h.u[4], l.u[4]); split2(a1.y, h.u[5], l.u[5]);
    split2(a1.z, h.u[6], l.u[6]); split2(a1.w, h.u[7], l.u[7]);
}
__device__ __forceinline__ float sigmoidf_(float x) {
    return 1.0f / (1.0f + __expf(-x));
}

// ---- split-cast weights f32 -> (hi, lo) bf16, once ----
__global__ __launch_bounds__(256) void cast_split(
    const float* __restrict__ in, unsigned short* __restrict__ hi,
    unsigned short* __restrict__ lo, int n4)
{
    int i = blockIdx.x * 256 + threadIdx.x;
    if (i < n4) {
        float4 v = ((const float4*)in)[i];
        ushort4 h, l;
        split2(v.x, h.x, l.x); split2(v.y, h.y, l.y);
        split2(v.z, h.z, l.z); split2(v.w, h.w, l.w);
        ((ushort4*)hi)[i] = h;
        ((ushort4*)lo)[i] = l;
    }
}

// ---- Phase 1: gi = X @ w_ih^T + b_ih. Split-bf16 MFMA (3 products). ----
// 128x128 tile, BK=64, 256 thr (4 waves, 2x2 quadrants). A (X) split
// in-register; B (w_ih) pre-split global bf16. Linear LDS writes with
// pre-swizzled k-slot; XOR-swizzled b128 reads (<=2-way, free).
__global__ __launch_bounds__(256, 2) void gemm_gi_mfma(
    const float* __restrict__ A,            // [M,512] fp32
    const unsigned short* __restrict__ Bh,  // [1536,512] bf16 hi
    const unsigned short* __restrict__ Bl,  // [1536,512] bf16 lo
    const float* __restrict__ bias,         // [1536]
    float* __restrict__ C)                  // [M,1536]
{
    __shared__ __attribute__((aligned(16))) unsigned char lds[65536];
    // A_hi[0,16K) A_lo[16K,32K) B_hi[32K,48K) B_lo[48K,64K)
    const int t = threadIdx.x;
    const int l = t & 63, w = t >> 6;
    const int nb = blockIdx.x, mb = blockIdx.y;
    const int p = t & 7;
    const int rbase = t >> 3;
    f32x4 acc[4][4] = {};

    for (int kk = 0; kk < 512; kk += 64) {
#pragma unroll
        for (int i = 0; i < 4; ++i) {
            const int r = i * 32 + rbase;            // tile row 0..127
            const int q = p ^ (r & 7);               // pre-swizzled k-slot
            const float* ga = A + (size_t)(mb * 128 + r) * 512 + kk + q * 8;
            SV ah, al;
            split8(*(const float4*)ga, *(const float4*)(ga + 4), ah, al);
            const int o = r * 128 + p * 16;
            *(short8v*)&lds[o] = ah.v;
            *(short8v*)&lds[16384 + o] = al.v;
            const size_t gb = (size_t)(nb * 128 + r) * 512 + kk + q * 8;
            *(short8v*)&lds[32768 + o] = *(const short8v*)(Bh + gb);
            *(short8v*)&lds[49152 + o] = *(const short8v*)(Bl + gb);
        }
        __syncthreads();
        const int mr0 = (w >> 1) * 64, nc0 = (w & 1) * 64;
#pragma unroll
        for (int kk2 = 0; kk2 < 2; ++kk2) {
            const int kap = kk2 * 4 + (l >> 4);
            short8v ah[4], al[4], bh[4], bl[4];
#pragma unroll
            for (int i = 0; i < 4; ++i) {
                const int row = mr0 + i * 16 + (l & 15);
                const int off = row * 128 + ((kap ^ (row & 7)) * 16);
                ah[i] = *(const short8v*)&lds[off];
                al[i] = *(const short8v*)&lds[16384 + off];
            }
#pragma unroll
            for (int j = 0; j < 4; ++j) {
                const int bn = nc0 + j * 16 + (l & 15);
                const int off = bn * 128 + ((kap ^ (bn & 7)) * 16);
                bh[j] = *(const short8v*)&lds[32768 + off];
                bl[j] = *(const short8v*)&lds[49152 + off];
            }
#pragma unroll
            for (int i = 0; i < 4; ++i)
#pragma unroll
                for (int j = 0; j < 4; ++j) {
                    acc[i][j] = __builtin_amdgcn_mfma_f32_16x16x32_bf16(ah[i], bh[j], acc[i][j], 0, 0, 0);
                    acc[i][j] = __builtin_amdgcn_mfma_f32_16x16x32_bf16(ah[i], bl[j], acc[i][j], 0, 0, 0);
                    acc[i][j] = __builtin_amdgcn_mfma_f32_16x16x32_bf16(al[i], bh[j], acc[i][j], 0, 0, 0);
                }
        }
        __syncthreads();
    }
    const int mr0 = (w >> 1) * 64, nc0 = (w & 1) * 64;
#pragma unroll
    for (int j = 0; j < 4; ++j) {
        const int col = nb * 128 + nc0 + j * 16 + (l & 15);
        const float bv = bias[col];
#pragma unroll
        for (int i = 0; i < 4; ++i) {
            const int row0 = mb * 128 + mr0 + i * 16 + (l >> 4) * 4;
#pragma unroll
            for (int rg = 0; rg < 4; ++rg)
                C[(size_t)(row0 + rg) * 1536 + col] = acc[i][j][rg] + bv;
        }
    }
}

// ---- Phase 2 tile body: one GRU step for tile (rt, ct). ----
// 16 rows x 16 h-cols x 3 gates, K=512 in BK=64 chunks, split-bf16 MFMA.
// w_hh pre-split (bf16 global); h fp32, split in-register (32 elem/thread).
__device__ __forceinline__ void gru_tile_body(
    unsigned char* lds,                        // 16 KB
    const float* __restrict__ gi_s,            // [256,1536]
    const unsigned short* __restrict__ whhH,   // bf16 hi [1536,512]
    const unsigned short* __restrict__ whhL,   // bf16 lo
    const float* __restrict__ bhh,             // [1536]
    const float* __restrict__ hold,            // fp32 [256,512]
    float* __restrict__ hnew,                  // fp32 [256,512]
    const int l, const int rt, const int ct)
{
    const int c0 = ct * 16, row0 = rt * 16;
    const int p = l & 7, rb = l >> 3;
    f32x4 acc[3] = {};

    for (int kk = 0; kk < 512; kk += 64) {
#pragma unroll
        for (int i = 0; i < 2; ++i) {          // A: h rows, 16x64, split in-reg
            const int r = i * 8 + rb;
            const int q = p ^ (r & 7);
            const float* g = hold + (size_t)(row0 + r) * 512 + kk + q * 8;
            SV h, lo;
            split8(*(const float4*)g, *(const float4*)(g + 4), h, lo);
            const int o = r * 128 + p * 16;
            *(short8v*)&lds[o] = h.v;
            *(short8v*)&lds[2048 + o] = lo.v;
        }
#pragma unroll
        for (int i = 0; i < 6; ++i) {          // B: 3 gates x 16 cols, 48x64
            const int r = i * 8 + rb;
            const int q = p ^ (r & 7);
            const int wrow = ((r >> 4) << 9) + c0 + (r & 15);
            const size_t g = (size_t)wrow * 512 + kk + q * 8;
            const int o = r * 128 + p * 16;
            *(short8v*)&lds[4096 + o]  = *(const short8v*)(whhH + g);
            *(short8v*)&lds[10240 + o] = *(const short8v*)(whhL + g);
        }
        __syncthreads();
#pragma unroll
        for (int kk2 = 0; kk2 < 2; ++kk2) {
            const int kap = kk2 * 4 + (l >> 4);
            const int arow = l & 15;
            const int aoff = arow * 128 + ((kap ^ (arow & 7)) * 16);
            const short8v ah = *(const short8v*)&lds[aoff];
            const short8v al = *(const short8v*)&lds[2048 + aoff];
#pragma unroll
            for (int j = 0; j < 3; ++j) {
                const int bn = j * 16 + (l & 15);
                const int boff = bn * 128 + ((kap ^ (bn & 7)) * 16);
                const short8v bh = *(const short8v*)&lds[4096 + boff];
                const short8v bl = *(const short8v*)&lds[10240 + boff];
                acc[j] = __builtin_amdgcn_mfma_f32_16x16x32_bf16(ah, bh, acc[j], 0, 0, 0);
                acc[j] = __builtin_amdgcn_mfma_f32_16x16x32_bf16(ah, bl, acc[j], 0, 0, 0);
                acc[j] = __builtin_amdgcn_mfma_f32_16x16x32_bf16(al, bh, acc[j], 0, 0, 0);
            }
        }
        __syncthreads();
    }
    const int col = c0 + (l & 15);
    const float br = bhh[col], bz = bhh[512 + col], bnn = bhh[1024 + col];
#pragma unroll
    for (int rg = 0; rg < 4; ++rg) {
        const int row = row0 + (l >> 4) * 4 + rg;
        const float* gp = gi_s + (size_t)row * 1536 + col;
        const float hv = hold[(size_t)row * 512 + col];
        const float r = sigmoidf_(gp[0]    + acc[0][rg] + br);
        const float z = sigmoidf_(gp[512]  + acc[1][rg] + bz);
        const float n = tanhf(gp[1024] + r * (acc[2][rg] + bnn));
        hnew[(size_t)row * 512 + col] = (1.0f - z) * n + z * hv;
    }
}

// ---- Phase 2a: cooperative persistent kernel — all tc steps, 1 launch. ----
// Grid 512 x 64 thr (2 blocks/CU). Step t parity picks ping-pong buffer
// (t=0 reads hA, writes hB; final h after t=255 lands in hA).
__global__ __launch_bounds__(64) void gru_coop(
    const float* __restrict__ gi,              // [tc,256,1536] chunk base
    const unsigned short* __restrict__ whhH,
    const unsigned short* __restrict__ whhL,
    const float* __restrict__ bhh,
    float* __restrict__ hA, float* __restrict__ hB,
    const int t0, const int tc)
{
    __shared__ __attribute__((aligned(16))) unsigned char lds[16384];
    cg::grid_group grid = cg::this_grid();
    const int l = threadIdx.x;
    const int ct = blockIdx.x & 31;
    const int rt = blockIdx.x >> 5;
    for (int s = 0; s < tc; ++s) {
        const int t = t0 + s;
        const float* hold = (t & 1) ? hB : hA;
        float* hnew = (t & 1) ? hA : hB;
        gru_tile_body(lds, gi + (size_t)s * 256 * 1536, whhH, whhL, bhh,
                      hold, hnew, l, rt, ct);
        grid.sync();
    }
}

// ---- Phase 2b: fallback — one step per launch (kernel boundary = barrier).
__global__ __launch_bounds__(64) void gru_step_fb(
    const float* __restrict__ gi_s,
    const unsigned short* __restrict__ whhH,
    const unsigned short* __restrict__ whhL,
    const float* __restrict__ bhh,
    const float* __restrict__ hold, float* __restrict__ hnew)
{
    __shared__ __attribute__((aligned(16))) unsigned char lds[16384];
    gru_tile_body(lds, gi_s, whhH, whhL, bhh, hold, hnew,
                  threadIdx.x, blockIdx.x >> 5, blockIdx.x & 31);
}

// ---- Phase 3 fp32 GEMM (exact; known-good) ----
template<bool TANH>
__global__ __launch_bounds__(256) void gemm_nt_bias(
    const float* __restrict__ A, const float* __restrict__ B,
    const float* __restrict__ bias, float* __restrict__ C,
    const int N, const int K)
{
    __shared__ float As[32][68];
    __shared__ float Bs[32][68];
    const int nb = blockIdx.x, mb = blockIdx.y;
    const int t  = threadIdx.x;
    const int tx = t & 15, ty = t >> 4;
    const int lr = t >> 3;
    const int lk = (t & 7) << 2;
    const float* pA = A + (size_t)(mb * 64 + lr) * K + lk;
    const float* pB = B + (size_t)(nb * 64 + lr) * K + lk;
    float acc[4][4];
#pragma unroll
    for (int i = 0; i < 4; ++i)
#pragma unroll
        for (int j = 0; j < 4; ++j) acc[i][j] = 0.0f;
    for (int kk = 0; kk < K; kk += 32) {
        const float4 a0 = *(const float4*)(pA + kk);
        const float4 a1 = *(const float4*)(pA + (size_t)32 * K + kk);
        const float4 b0 = *(const float4*)(pB + kk);
        const float4 b1 = *(const float4*)(pB + (size_t)32 * K + kk);
        __syncthreads();
        As[lk+0][lr] = a0.x; As[lk+1][lr] = a0.y; As[lk+2][lr] = a0.z; As[lk+3][lr] = a0.w;
        As[lk+0][lr+32] = a1.x; As[lk+1][lr+32] = a1.y; As[lk+2][lr+32] = a1.z; As[lk+3][lr+32] = a1.w;
        Bs[lk+0][lr] = b0.x; Bs[lk+1][lr] = b0.y; Bs[lk+2][lr] = b0.z; Bs[lk+3][lr] = b0.w;
        Bs[lk+0][lr+32] = b1.x; Bs[lk+1][lr+32] = b1.y; Bs[lk+2][lr+32] = b1.z; Bs[lk+3][lr+32] = b1.w;
        __syncthreads();
#pragma unroll
        for (int k = 0; k < 32; ++k) {
            const float4 av = *(const float4*)&As[k][ty << 2];
            const float4 bv = *(const float4*)&Bs[k][tx << 2];
            acc[0][0] += av.x * bv.x; acc[0][1] += av.x * bv.y; acc[0][2] += av.x * bv.z; acc[0][3] += av.x * bv.w;
            acc[1][0] += av.y * bv.x; acc[1][1] += av.y * bv.y; acc[1][2] += av.y * bv.z; acc[1][3] += av.y * bv.w;
            acc[2][0] += av.z * bv.x; acc[2][1] += av.z * bv.y; acc[2][2] += av.z * bv.z; acc[2][3] += av.z * bv.w;
            acc[3][0] += av.w * bv.x; acc[3][1] += av.w * bv.y; acc[3][2] += av.w * bv.z; acc[3][3] += av.w * bv.w;
        }
    }
    const int crow = mb * 64 + (ty << 2);
    const int ccol = nb * 64 + (tx << 2);
    const float4 bv = *(const float4*)(bias + ccol);
#pragma unroll
    for (int i = 0; i < 4; ++i) {
        float4 o;
        o.x = acc[i][0] + bv.x; o.y = acc[i][1] + bv.y;
        o.z = acc[i][2] + bv.z; o.w = acc[i][3] + bv.w;
        if (TANH) { o.x = tanhf(o.x); o.y = tanhf(o.y); o.z = tanhf(o.z); o.w = tanhf(o.w); }
        *(float4*)(C + (size_t)(crow + i) * N + ccol) = o;
    }
}

__global__ __launch_bounds__(256) void value_head(
    const float* __restrict__ out1, const float* __restrict__ W2,
    const float* __restrict__ b2, float* __restrict__ out)
{
    const int b = blockIdx.x, t = threadIdx.x;
    float p = out1[(size_t)b * 512 + t] * W2[t]
            + out1[(size_t)b * 512 + 256 + t] * W2[256 + t];
#pragma unroll
    for (int off = 32; off > 0; off >>= 1) p += __shfl_down(p, off, 64);
    __shared__ float ps[4];
    if ((t & 63) == 0) ps[t >> 6] = p;
    __syncthreads();
    if (t == 0) out[b] = tanhf(ps[0] + ps[1] + ps[2] + ps[3] + b2[0]);
}

extern "C" void kernel_launch(void* const* d_in, const int* in_sizes, int n_in,
                              void* d_out, int out_size, void* d_ws, size_t ws_size,
                              hipStream_t stream)
{
    (void)in_sizes; (void)n_in; (void)out_size;
    const float* input = (const float*)d_in[0];   // [256,256,512]
    const float* w_ih  = (const float*)d_in[1];   // [1536,512]
    const float* w_hh  = (const float*)d_in[2];   // [1536,512]
    const float* b_ih  = (const float*)d_in[3];   // [1536]
    const float* b_hh  = (const float*)d_in[4];   // [1536]
    const float* W1    = (const float*)d_in[5];   // [512,512]
    const float* b1    = (const float*)d_in[6];   // [512]
    const float* W2    = (const float*)d_in[7];   // [512]
    const float* b2    = (const float*)d_in[8];   // [1]
    float* out = (float*)d_out;
    float* ws  = (float*)d_ws;

    // ws layout in FLOAT SLOTS. One [1536,512] bf16 buffer = 786432 ushorts
    // = 1,572,864 B = 393,216 float slots (NOT 196,608 — the R4 bug).
    float* hA = ws;                                        // [0, 131072)
    float* hB = ws + 131072;                               // [131072, 262144)
    float* o1 = ws + 262144;                               // [262144, 393216)
    unsigned short* wihH = (unsigned short*)(ws + 393216); // [393216, 786432)
    unsigned short* wihL = (unsigned short*)(ws + 786432); // [786432, 1179648)
    unsigned short* whhH = (unsigned short*)(ws + 1179648);// [1179648, 1572864)
    unsigned short* whhL = (unsigned short*)(ws + 1572864);// [1572864, 1966080)
    float* gi = ws + 1966080;

    const size_t per_step = 256 * 1536;             // gi floats per timestep
    const size_t base = 1966080;
    const size_t avail = (ws_size / 4 > base) ? ws_size / 4 - base : 0;
    int Tc = (int)(avail / per_step);
    if (Tc > 256) Tc = 256;
    if (Tc < 1) Tc = 1;

    hipMemsetAsync(hA, 0, 131072 * sizeof(float), stream);   // h(-1) = 0

    cast_split<<<768, 256, 0, stream>>>(w_ih, wihH, wihL, 196608);
    cast_split<<<768, 256, 0, stream>>>(w_hh, whhH, whhL, 196608);

    for (int t0 = 0; t0 < 256; t0 += Tc) {
        const int tc = (t0 + Tc <= 256) ? Tc : (256 - t0);
        const int Mc = tc * 256;
        // Phase 1 (chunk): gi = X_chunk @ w_ih^T + b_ih
        gemm_gi_mfma<<<dim3(12, Mc / 128), 256, 0, stream>>>(
            input + (size_t)t0 * 256 * 512, wihH, wihL, b_ih, gi);
        // Phase 2 (chunk): cooperative persistent kernel; rc-checked fallback.
        {
            const float* a_gi = gi;
            const unsigned short* a_wh = whhH; const unsigned short* a_wl = whhL;
            const float* a_bh = b_hh;
            float* a_hA = hA; float* a_hB = hB;
            int a_t0 = t0; int a_tc = tc;
            void* args[] = {&a_gi, &a_wh, &a_wl, &a_bh, &a_hA, &a_hB, &a_t0, &a_tc};
            hipError_t rc = hipLaunchCooperativeKernel(
                (const void*)gru_coop, dim3(512), dim3(64), args, 0, stream);
            if (rc != hipSuccess) {
                // Fallback: per-step launches (kernel boundary = grid barrier)
                for (int s = 0; s < tc; ++s) {
                    const int t = t0 + s;
                    const float* hold = (t & 1) ? hB : hA;
                    float* hnew = (t & 1) ? hA : hB;
                    gru_step_fb<<<dim3(512), 64, 0, stream>>>(
                        gi + (size_t)s * per_step, whhH, whhL, b_hh, hold, hnew);
                }
            }
        }
    }

    // Phase 3: final h is in hA (after 256 steps, even count).
    gemm_nt_bias<true><<<dim3(512 / 64, 256 / 64), 256, 0, stream>>>(
        hA, W1, b1, o1, 512, 512);
    value_head<<<256, 256, 0, stream>>>(o1, W2, b2, out);
}

// Round 7
// 14862.990 us; speedup vs baseline: 1.3782x; 1.3782x over previous
//
#include <hip/hip_runtime.h>
#include <hip/hip_bf16.h>

typedef __attribute__((ext_vector_type(8))) short short8v;   // 8 bf16 = 16 B
typedef __attribute__((ext_vector_type(4))) float f32x4;

union SV { short8v v; unsigned short u[8]; };
union FU { float f; unsigned u; };

// Truncation split: x ~= hi + lo, residual <= 2^-16 |x|.
__device__ __forceinline__ void split2(float x, unsigned short& hi, unsigned short& lo) {
    FU a; a.f = x;
    hi = (unsigned short)(a.u >> 16);
    FU h; h.u = a.u & 0xffff0000u;
    FU r; r.f = x - h.f;              // exact
    lo = (unsigned short)(r.u >> 16);
}
__device__ __forceinline__ void split8(const float4 a0, const float4 a1, SV& h, SV& l) {
    split2(a0.x, h.u[0], l.u[0]); split2(a0.y, h.u[1], l.u[1]);
    split2(a0.z, h.u[2], l.u[2]); split2(a0.w, h.u[3], l.u[3]);
    split2(a1.x, h.u[4], l.u[4]); split2(a1.y, h.u[5], l.u[5]);
    split2(a1.z, h.u[6], l.u[6]); split2(a1.w, h.u[7], l.u[7]);
}
__device__ __forceinline__ float sigmoidf_(float x) {
    return 1.0f / (1.0f + __expf(-x));
}

// Hand-rolled grid barrier (cg::grid.sync measured at ~78us/step in R6).
// Single monotonic counter: arrive = agent-scope fetch_add; wait until
// cnt >= total*gen. __threadfence (release/wbl2) before arrive makes this
// block's h writes LLC-visible; acquire fence after wait invalidates the
// local XCD L2 so next-step reads are fresh. Blocks are 1 wave (64 thr),
// so the masked spin + unmasked fence + __syncthreads is race-free.
__device__ __forceinline__ void grid_barrier(unsigned* cnt, unsigned gen, unsigned total) {
    __syncthreads();                         // block's stores issued & drained
    if (threadIdx.x == 0) {
        __threadfence();                     // agent release (L2 writeback)
        __hip_atomic_fetch_add(cnt, 1u, __ATOMIC_RELAXED, __HIP_MEMORY_SCOPE_AGENT);
        while (__hip_atomic_load(cnt, __ATOMIC_RELAXED, __HIP_MEMORY_SCOPE_AGENT)
               < total * gen)
            __builtin_amdgcn_s_sleep(2);
    }
    __builtin_amdgcn_fence(__ATOMIC_ACQUIRE, "agent");  // L2 invalidate
    __syncthreads();
}

// ---- split-cast weights f32 -> (hi, lo) bf16, once ----
__global__ __launch_bounds__(256) void cast_split(
    const float* __restrict__ in, unsigned short* __restrict__ hi,
    unsigned short* __restrict__ lo, int n4)
{
    int i = blockIdx.x * 256 + threadIdx.x;
    if (i < n4) {
        float4 v = ((const float4*)in)[i];
        ushort4 h, l;
        split2(v.x, h.x, l.x); split2(v.y, h.y, l.y);
        split2(v.z, h.z, l.z); split2(v.w, h.w, l.w);
        ((ushort4*)hi)[i] = h;
        ((ushort4*)lo)[i] = l;
    }
}

// ---- Phase 1: gi = X @ w_ih^T + b_ih. Split-bf16 MFMA (3 products). ----
// 128x128 tile, BK=64, 256 thr (4 waves, 2x2 quadrants). A (X) split
// in-register; B (w_ih) pre-split global bf16. Linear LDS writes with
// pre-swizzled k-slot; XOR-swizzled b128 reads (<=2-way, free).
__global__ __launch_bounds__(256, 2) void gemm_gi_mfma(
    const float* __restrict__ A,            // [M,512] fp32
    const unsigned short* __restrict__ Bh,  // [1536,512] bf16 hi
    const unsigned short* __restrict__ Bl,  // [1536,512] bf16 lo
    const float* __restrict__ bias,         // [1536]
    float* __restrict__ C)                  // [M,1536]
{
    __shared__ __attribute__((aligned(16))) unsigned char lds[65536];
    // A_hi[0,16K) A_lo[16K,32K) B_hi[32K,48K) B_lo[48K,64K)
    const int t = threadIdx.x;
    const int l = t & 63, w = t >> 6;
    const int nb = blockIdx.x, mb = blockIdx.y;
    const int p = t & 7;
    const int rbase = t >> 3;
    f32x4 acc[4][4] = {};

    for (int kk = 0; kk < 512; kk += 64) {
#pragma unroll
        for (int i = 0; i < 4; ++i) {
            const int r = i * 32 + rbase;            // tile row 0..127
            const int q = p ^ (r & 7);               // pre-swizzled k-slot
            const float* ga = A + (size_t)(mb * 128 + r) * 512 + kk + q * 8;
            SV ah, al;
            split8(*(const float4*)ga, *(const float4*)(ga + 4), ah, al);
            const int o = r * 128 + p * 16;
            *(short8v*)&lds[o] = ah.v;
            *(short8v*)&lds[16384 + o] = al.v;
            const size_t gb = (size_t)(nb * 128 + r) * 512 + kk + q * 8;
            *(short8v*)&lds[32768 + o] = *(const short8v*)(Bh + gb);
            *(short8v*)&lds[49152 + o] = *(const short8v*)(Bl + gb);
        }
        __syncthreads();
        const int mr0 = (w >> 1) * 64, nc0 = (w & 1) * 64;
#pragma unroll
        for (int kk2 = 0; kk2 < 2; ++kk2) {
            const int kap = kk2 * 4 + (l >> 4);
            short8v ah[4], al[4], bh[4], bl[4];
#pragma unroll
            for (int i = 0; i < 4; ++i) {
                const int row = mr0 + i * 16 + (l & 15);
                const int off = row * 128 + ((kap ^ (row & 7)) * 16);
                ah[i] = *(const short8v*)&lds[off];
                al[i] = *(const short8v*)&lds[16384 + off];
            }
#pragma unroll
            for (int j = 0; j < 4; ++j) {
                const int bn = nc0 + j * 16 + (l & 15);
                const int off = bn * 128 + ((kap ^ (bn & 7)) * 16);
                bh[j] = *(const short8v*)&lds[32768 + off];
                bl[j] = *(const short8v*)&lds[49152 + off];
            }
#pragma unroll
            for (int i = 0; i < 4; ++i)
#pragma unroll
                for (int j = 0; j < 4; ++j) {
                    acc[i][j] = __builtin_amdgcn_mfma_f32_16x16x32_bf16(ah[i], bh[j], acc[i][j], 0, 0, 0);
                    acc[i][j] = __builtin_amdgcn_mfma_f32_16x16x32_bf16(ah[i], bl[j], acc[i][j], 0, 0, 0);
                    acc[i][j] = __builtin_amdgcn_mfma_f32_16x16x32_bf16(al[i], bh[j], acc[i][j], 0, 0, 0);
                }
        }
        __syncthreads();
    }
    const int mr0 = (w >> 1) * 64, nc0 = (w & 1) * 64;
#pragma unroll
    for (int j = 0; j < 4; ++j) {
        const int col = nb * 128 + nc0 + j * 16 + (l & 15);
        const float bv = bias[col];
#pragma unroll
        for (int i = 0; i < 4; ++i) {
            const int row0 = mb * 128 + mr0 + i * 16 + (l >> 4) * 4;
#pragma unroll
            for (int rg = 0; rg < 4; ++rg)
                C[(size_t)(row0 + rg) * 1536 + col] = acc[i][j][rg] + bv;
        }
    }
}

// ---- Phase 2 tile body: one GRU step for tile (rt, ct). ----
// 16 rows x 16 h-cols x 3 gates, K=512 in BK=64 chunks, split-bf16 MFMA.
// w_hh pre-split (bf16 global); h fp32, split in-register.
__device__ __forceinline__ void gru_tile_body(
    unsigned char* lds,                        // 16 KB
    const float* __restrict__ gi_s,            // [256,1536]
    const unsigned short* __restrict__ whhH,   // bf16 hi [1536,512]
    const unsigned short* __restrict__ whhL,   // bf16 lo
    const float* __restrict__ bhh,             // [1536]
    const float* __restrict__ hold,            // fp32 [256,512]
    float* __restrict__ hnew,                  // fp32 [256,512]
    const int l, const int rt, const int ct)
{
    const int c0 = ct * 16, row0 = rt * 16;
    const int p = l & 7, rb = l >> 3;
    f32x4 acc[3] = {};

    for (int kk = 0; kk < 512; kk += 64) {
#pragma unroll
        for (int i = 0; i < 2; ++i) {          // A: h rows, 16x64, split in-reg
            const int r = i * 8 + rb;
            const int q = p ^ (r & 7);
            const float* g = hold + (size_t)(row0 + r) * 512 + kk + q * 8;
            SV h, lo;
            split8(*(const float4*)g, *(const float4*)(g + 4), h, lo);
            const int o = r * 128 + p * 16;
            *(short8v*)&lds[o] = h.v;
            *(short8v*)&lds[2048 + o] = lo.v;
        }
#pragma unroll
        for (int i = 0; i < 6; ++i) {          // B: 3 gates x 16 cols, 48x64
            const int r = i * 8 + rb;
            const int q = p ^ (r & 7);
            const int wrow = ((r >> 4) << 9) + c0 + (r & 15);
            const size_t g = (size_t)wrow * 512 + kk + q * 8;
            const int o = r * 128 + p * 16;
            *(short8v*)&lds[4096 + o]  = *(const short8v*)(whhH + g);
            *(short8v*)&lds[10240 + o] = *(const short8v*)(whhL + g);
        }
        __syncthreads();
#pragma unroll
        for (int kk2 = 0; kk2 < 2; ++kk2) {
            const int kap = kk2 * 4 + (l >> 4);
            const int arow = l & 15;
            const int aoff = arow * 128 + ((kap ^ (arow & 7)) * 16);
            const short8v ah = *(const short8v*)&lds[aoff];
            const short8v al = *(const short8v*)&lds[2048 + aoff];
#pragma unroll
            for (int j = 0; j < 3; ++j) {
                const int bn = j * 16 + (l & 15);
                const int boff = bn * 128 + ((kap ^ (bn & 7)) * 16);
                const short8v bh = *(const short8v*)&lds[4096 + boff];
                const short8v bl = *(const short8v*)&lds[10240 + boff];
                acc[j] = __builtin_amdgcn_mfma_f32_16x16x32_bf16(ah, bh, acc[j], 0, 0, 0);
                acc[j] = __builtin_amdgcn_mfma_f32_16x16x32_bf16(ah, bl, acc[j], 0, 0, 0);
                acc[j] = __builtin_amdgcn_mfma_f32_16x16x32_bf16(al, bh, acc[j], 0, 0, 0);
            }
        }
        __syncthreads();
    }
    const int col = c0 + (l & 15);
    const float br = bhh[col], bz = bhh[512 + col], bnn = bhh[1024 + col];
#pragma unroll
    for (int rg = 0; rg < 4; ++rg) {
        const int row = row0 + (l >> 4) * 4 + rg;
        const float* gp = gi_s + (size_t)row * 1536 + col;
        const float hv = hold[(size_t)row * 512 + col];
        const float r = sigmoidf_(gp[0]    + acc[0][rg] + br);
        const float z = sigmoidf_(gp[512]  + acc[1][rg] + bz);
        const float n = tanhf(gp[1024] + r * (acc[2][rg] + bnn));
        hnew[(size_t)row * 512 + col] = (1.0f - z) * n + z * hv;
    }
}

// ---- Phase 2a: cooperative persistent kernel — all tc steps, 1 launch. ----
// Grid 512 x 64 thr. Custom barrier (gen = absolute step + 1, monotonic;
// counter zeroed once per kernel_launch). Last step of the chunk skips the
// barrier (kernel end is a release point).
__global__ __launch_bounds__(64) void gru_coop(
    const float* __restrict__ gi,              // [tc,256,1536] chunk base
    const unsigned short* __restrict__ whhH,
    const unsigned short* __restrict__ whhL,
    const float* __restrict__ bhh,
    float* __restrict__ hA, float* __restrict__ hB,
    unsigned* __restrict__ bar,
    const int t0, const int tc)
{
    __shared__ __attribute__((aligned(16))) unsigned char lds[16384];
    const int l = threadIdx.x;
    const int ct = blockIdx.x & 31;
    const int rt = blockIdx.x >> 5;
    for (int s = 0; s < tc; ++s) {
        const int t = t0 + s;
        const float* hold = (t & 1) ? hB : hA;
        float* hnew = (t & 1) ? hA : hB;
        gru_tile_body(lds, gi + (size_t)s * 256 * 1536, whhH, whhL, bhh,
                      hold, hnew, l, rt, ct);
        if (s + 1 < tc)
            grid_barrier(bar, (unsigned)(t + 1), 512u);
    }
}

// ---- Phase 2b: fallback — one step per launch (kernel boundary = barrier).
__global__ __launch_bounds__(64) void gru_step_fb(
    const float* __restrict__ gi_s,
    const unsigned short* __restrict__ whhH,
    const unsigned short* __restrict__ whhL,
    const float* __restrict__ bhh,
    const float* __restrict__ hold, float* __restrict__ hnew)
{
    __shared__ __attribute__((aligned(16))) unsigned char lds[16384];
    gru_tile_body(lds, gi_s, whhH, whhL, bhh, hold, hnew,
                  threadIdx.x, blockIdx.x >> 5, blockIdx.x & 31);
}

// ---- Phase 3 fp32 GEMM (exact; known-good) ----
template<bool TANH>
__global__ __launch_bounds__(256) void gemm_nt_bias(
    const float* __restrict__ A, const float* __restrict__ B,
    const float* __restrict__ bias, float* __restrict__ C,
    const int N, const int K)
{
    __shared__ float As[32][68];
    __shared__ float Bs[32][68];
    const int nb = blockIdx.x, mb = blockIdx.y;
    const int t  = threadIdx.x;
    const int tx = t & 15, ty = t >> 4;
    const int lr = t >> 3;
    const int lk = (t & 7) << 2;
    const float* pA = A + (size_t)(mb * 64 + lr) * K + lk;
    const float* pB = B + (size_t)(nb * 64 + lr) * K + lk;
    float acc[4][4];
#pragma unroll
    for (int i = 0; i < 4; ++i)
#pragma unroll
        for (int j = 0; j < 4; ++j) acc[i][j] = 0.0f;
    for (int kk = 0; kk < K; kk += 32) {
        const float4 a0 = *(const float4*)(pA + kk);
        const float4 a1 = *(const float4*)(pA + (size_t)32 * K + kk);
        const float4 b0 = *(const float4*)(pB + kk);
        const float4 b1 = *(const float4*)(pB + (size_t)32 * K + kk);
        __syncthreads();
        As[lk+0][lr] = a0.x; As[lk+1][lr] = a0.y; As[lk+2][lr] = a0.z; As[lk+3][lr] = a0.w;
        As[lk+0][lr+32] = a1.x; As[lk+1][lr+32] = a1.y; As[lk+2][lr+32] = a1.z; As[lk+3][lr+32] = a1.w;
        Bs[lk+0][lr] = b0.x; Bs[lk+1][lr] = b0.y; Bs[lk+2][lr] = b0.z; Bs[lk+3][lr] = b0.w;
        Bs[lk+0][lr+32] = b1.x; Bs[lk+1][lr+32] = b1.y; Bs[lk+2][lr+32] = b1.z; Bs[lk+3][lr+32] = b1.w;
        __syncthreads();
#pragma unroll
        for (int k = 0; k < 32; ++k) {
            const float4 av = *(const float4*)&As[k][ty << 2];
            const float4 bv = *(const float4*)&Bs[k][tx << 2];
            acc[0][0] += av.x * bv.x; acc[0][1] += av.x * bv.y; acc[0][2] += av.x * bv.z; acc[0][3] += av.x * bv.w;
            acc[1][0] += av.y * bv.x; acc[1][1] += av.y * bv.y; acc[1][2] += av.y * bv.z; acc[1][3] += av.y * bv.w;
            acc[2][0] += av.z * bv.x; acc[2][1] += av.z * bv.y; acc[2][2] += av.z * bv.z; acc[2][3] += av.z * bv.w;
            acc[3][0] += av.w * bv.x; acc[3][1] += av.w * bv.y; acc[3][2] += av.w * bv.z; acc[3][3] += av.w * bv.w;
        }
    }
    const int crow = mb * 64 + (ty << 2);
    const int ccol = nb * 64 + (tx << 2);
    const float4 bv = *(const float4*)(bias + ccol);
#pragma unroll
    for (int i = 0; i < 4; ++i) {
        float4 o;
        o.x = acc[i][0] + bv.x; o.y = acc[i][1] + bv.y;
        o.z = acc[i][2] + bv.z; o.w = acc[i][3] + bv.w;
        if (TANH) { o.x = tanhf(o.x); o.y = tanhf(o.y); o.z = tanhf(o.z); o.w = tanhf(o.w); }
        *(float4*)(C + (size_t)(crow + i) * N + ccol) = o;
    }
}

__global__ __launch_bounds__(256) void value_head(
    const float* __restrict__ out1, const float* __restrict__ W2,
    const float* __restrict__ b2, float* __restrict__ out)
{
    const int b = blockIdx.x, t = threadIdx.x;
    float p = out1[(size_t)b * 512 + t] * W2[t]
            + out1[(size_t)b * 512 + 256 + t] * W2[256 + t];
#pragma unroll
    for (int off = 32; off > 0; off >>= 1) p += __shfl_down(p, off, 64);
    __shared__ float ps[4];
    if ((t & 63) == 0) ps[t >> 6] = p;
    __syncthreads();
    if (t == 0) out[b] = tanhf(ps[0] + ps[1] + ps[2] + ps[3] + b2[0]);
}

extern "C" void kernel_launch(void* const* d_in, const int* in_sizes, int n_in,
                              void* d_out, int out_size, void* d_ws, size_t ws_size,
                              hipStream_t stream)
{
    (void)in_sizes; (void)n_in; (void)out_size;
    const float* input = (const float*)d_in[0];   // [256,256,512]
    const float* w_ih  = (const float*)d_in[1];   // [1536,512]
    const float* w_hh  = (const float*)d_in[2];   // [1536,512]
    const float* b_ih  = (const float*)d_in[3];   // [1536]
    const float* b_hh  = (const float*)d_in[4];   // [1536]
    const float* W1    = (const float*)d_in[5];   // [512,512]
    const float* b1    = (const float*)d_in[6];   // [512]
    const float* W2    = (const float*)d_in[7];   // [512]
    const float* b2    = (const float*)d_in[8];   // [1]
    float* out = (float*)d_out;
    float* ws  = (float*)d_ws;

    // ws layout in FLOAT SLOTS. One [1536,512] bf16 buffer = 786432 ushorts
    // = 1,572,864 B = 393,216 float slots.
    float* hA = ws;                                        // [0, 131072)
    float* hB = ws + 131072;                               // [131072, 262144)
    float* o1 = ws + 262144;                               // [262144, 393216)
    unsigned short* wihH = (unsigned short*)(ws + 393216); // [393216, 786432)
    unsigned short* wihL = (unsigned short*)(ws + 786432); // [786432, 1179648)
    unsigned short* whhH = (unsigned short*)(ws + 1179648);// [1179648, 1572864)
    unsigned short* whhL = (unsigned short*)(ws + 1572864);// [1572864, 1966080)
    unsigned* bar = (unsigned*)(ws + 1966080);             // [1966080, 1966336)
    float* gi = ws + 1966336;

    const size_t per_step = 256 * 1536;             // gi floats per timestep
    const size_t base = 1966336;
    const size_t avail = (ws_size / 4 > base) ? ws_size / 4 - base : 0;
    int Tc = (int)(avail / per_step);
    if (Tc > 256) Tc = 256;
    if (Tc < 1) Tc = 1;

    hipMemsetAsync(hA, 0, 131072 * sizeof(float), stream);   // h(-1) = 0
    hipMemsetAsync(bar, 0, 256 * sizeof(unsigned), stream);  // barrier gen 0

    cast_split<<<768, 256, 0, stream>>>(w_ih, wihH, wihL, 196608);
    cast_split<<<768, 256, 0, stream>>>(w_hh, whhH, whhL, 196608);

    for (int t0 = 0; t0 < 256; t0 += Tc) {
        const int tc = (t0 + Tc <= 256) ? Tc : (256 - t0);
        const int Mc = tc * 256;
        // Phase 1 (chunk): gi = X_chunk @ w_ih^T + b_ih
        gemm_gi_mfma<<<dim3(12, Mc / 128), 256, 0, stream>>>(
            input + (size_t)t0 * 256 * 512, wihH, wihL, b_ih, gi);
        // Phase 2 (chunk): coop persistent kernel + custom barrier.
        {
            const float* a_gi = gi;
            const unsigned short* a_wh = whhH; const unsigned short* a_wl = whhL;
            const float* a_bh = b_hh;
            float* a_hA = hA; float* a_hB = hB;
            unsigned* a_bar = bar;
            int a_t0 = t0; int a_tc = tc;
            void* args[] = {&a_gi, &a_wh, &a_wl, &a_bh, &a_hA, &a_hB, &a_bar, &a_t0, &a_tc};
            hipError_t rc = hipLaunchCooperativeKernel(
                (const void*)gru_coop, dim3(512), dim3(64), args, 0, stream);
            if (rc != hipSuccess) {
                // Fallback: per-step launches (kernel boundary = grid barrier)
                for (int s = 0; s < tc; ++s) {
                    const int t = t0 + s;
                    const float* hold = (t & 1) ? hB : hA;
                    float* hnew = (t & 1) ? hA : hB;
                    gru_step_fb<<<dim3(512), 64, 0, stream>>>(
                        gi + (size_t)s * per_step, whhH, whhL, b_hh, hold, hnew);
                }
            }
        }
    }

    // Phase 3: final h is in hA (after 256 steps, even count).
    gemm_nt_bias<true><<<dim3(512 / 64, 256 / 64), 256, 0, stream>>>(
        hA, W1, b1, o1, 512, 512);
    value_head<<<256, 256, 0, stream>>>(o1, W2, b2, out);
}

// Round 8
// 11288.289 us; speedup vs baseline: 1.8146x; 1.3167x over previous
//
#include <hip/hip_runtime.h>
#include <hip/hip_bf16.h>

typedef __attribute__((ext_vector_type(8))) short short8v;   // 8 bf16 = 16 B
typedef __attribute__((ext_vector_type(4))) float f32x4;

union SV { short8v v; unsigned short u[8]; };
union FU { float f; unsigned u; };

// Truncation split: x ~= hi + lo, residual <= 2^-16 |x|.
__device__ __forceinline__ void split2(float x, unsigned short& hi, unsigned short& lo) {
    FU a; a.f = x;
    hi = (unsigned short)(a.u >> 16);
    FU h; h.u = a.u & 0xffff0000u;
    FU r; r.f = x - h.f;              // exact
    lo = (unsigned short)(r.u >> 16);
}
__device__ __forceinline__ void split8(const float4 a0, const float4 a1, SV& h, SV& l) {
    split2(a0.x, h.u[0], l.u[0]); split2(a0.y, h.u[1], l.u[1]);
    split2(a0.z, h.u[2], l.u[2]); split2(a0.w, h.u[3], l.u[3]);
    split2(a1.x, h.u[4], l.u[4]); split2(a1.y, h.u[5], l.u[5]);
    split2(a1.z, h.u[6], l.u[6]); split2(a1.w, h.u[7], l.u[7]);
}
__device__ __forceinline__ float sigmoidf_(float x) {
    return 1.0f / (1.0f + __expf(-x));
}

// Flag-array grid barrier. R7's single-counter version cost ~52us/step:
// 512 fetch_adds to ONE LLC line serialize (~100ns/RMW). Here arrive is a
// plain device-scope store to flags[bid] (512 distinct addresses, no RMW,
// no serialization); wait is each wave polling all 512 flags via 4 u64
// agent loads/lane + __all. gen is monotonic (no reset between steps);
// flags are zeroed once per kernel_launch (replay-safe). Blocks are 1 wave.
__device__ __forceinline__ void grid_barrier_flags(
    unsigned* __restrict__ flags, unsigned gen)
{
    __syncthreads();                     // wave's h stores drained (vmcnt 0)
    if (threadIdx.x == 0) {
        __threadfence();                 // release: L2 writeback -> LLC
        __hip_atomic_store(&flags[blockIdx.x], gen,
                           __ATOMIC_RELAXED, __HIP_MEMORY_SCOPE_AGENT);
    }
    const unsigned long long* f64 =
        (const unsigned long long*)flags + (threadIdx.x << 2);
    for (;;) {
        bool ok = true;
#pragma unroll
        for (int i = 0; i < 4; ++i) {
            unsigned long long v = __hip_atomic_load(
                &f64[i], __ATOMIC_RELAXED, __HIP_MEMORY_SCOPE_AGENT);
            ok = ok && ((unsigned)v >= gen) && ((unsigned)(v >> 32) >= gen);
        }
        if (__all(ok)) break;
        __builtin_amdgcn_s_sleep(1);
    }
    __builtin_amdgcn_fence(__ATOMIC_ACQUIRE, "agent");  // invalidate local L2
    __syncthreads();
}

// ---- split-cast weights f32 -> (hi, lo) bf16, once ----
__global__ __launch_bounds__(256) void cast_split(
    const float* __restrict__ in, unsigned short* __restrict__ hi,
    unsigned short* __restrict__ lo, int n4)
{
    int i = blockIdx.x * 256 + threadIdx.x;
    if (i < n4) {
        float4 v = ((const float4*)in)[i];
        ushort4 h, l;
        split2(v.x, h.x, l.x); split2(v.y, h.y, l.y);
        split2(v.z, h.z, l.z); split2(v.w, h.w, l.w);
        ((ushort4*)hi)[i] = h;
        ((ushort4*)lo)[i] = l;
    }
}

// ---- Phase 1: gi = X @ w_ih^T + b_ih. Split-bf16 MFMA (3 products). ----
// 128x128 tile, BK=64, 256 thr (4 waves, 2x2 quadrants). A (X) split
// in-register; B (w_ih) pre-split global bf16. Linear LDS writes with
// pre-swizzled k-slot; XOR-swizzled b128 reads (<=2-way, free).
__global__ __launch_bounds__(256, 2) void gemm_gi_mfma(
    const float* __restrict__ A,            // [M,512] fp32
    const unsigned short* __restrict__ Bh,  // [1536,512] bf16 hi
    const unsigned short* __restrict__ Bl,  // [1536,512] bf16 lo
    const float* __restrict__ bias,         // [1536]
    float* __restrict__ C)                  // [M,1536]
{
    __shared__ __attribute__((aligned(16))) unsigned char lds[65536];
    // A_hi[0,16K) A_lo[16K,32K) B_hi[32K,48K) B_lo[48K,64K)
    const int t = threadIdx.x;
    const int l = t & 63, w = t >> 6;
    const int nb = blockIdx.x, mb = blockIdx.y;
    const int p = t & 7;
    const int rbase = t >> 3;
    f32x4 acc[4][4] = {};

    for (int kk = 0; kk < 512; kk += 64) {
#pragma unroll
        for (int i = 0; i < 4; ++i) {
            const int r = i * 32 + rbase;            // tile row 0..127
            const int q = p ^ (r & 7);               // pre-swizzled k-slot
            const float* ga = A + (size_t)(mb * 128 + r) * 512 + kk + q * 8;
            SV ah, al;
            split8(*(const float4*)ga, *(const float4*)(ga + 4), ah, al);
            const int o = r * 128 + p * 16;
            *(short8v*)&lds[o] = ah.v;
            *(short8v*)&lds[16384 + o] = al.v;
            const size_t gb = (size_t)(nb * 128 + r) * 512 + kk + q * 8;
            *(short8v*)&lds[32768 + o] = *(const short8v*)(Bh + gb);
            *(short8v*)&lds[49152 + o] = *(const short8v*)(Bl + gb);
        }
        __syncthreads();
        const int mr0 = (w >> 1) * 64, nc0 = (w & 1) * 64;
#pragma unroll
        for (int kk2 = 0; kk2 < 2; ++kk2) {
            const int kap = kk2 * 4 + (l >> 4);
            short8v ah[4], al[4], bh[4], bl[4];
#pragma unroll
            for (int i = 0; i < 4; ++i) {
                const int row = mr0 + i * 16 + (l & 15);
                const int off = row * 128 + ((kap ^ (row & 7)) * 16);
                ah[i] = *(const short8v*)&lds[off];
                al[i] = *(const short8v*)&lds[16384 + off];
            }
#pragma unroll
            for (int j = 0; j < 4; ++j) {
                const int bn = nc0 + j * 16 + (l & 15);
                const int off = bn * 128 + ((kap ^ (bn & 7)) * 16);
                bh[j] = *(const short8v*)&lds[32768 + off];
                bl[j] = *(const short8v*)&lds[49152 + off];
            }
#pragma unroll
            for (int i = 0; i < 4; ++i)
#pragma unroll
                for (int j = 0; j < 4; ++j) {
                    acc[i][j] = __builtin_amdgcn_mfma_f32_16x16x32_bf16(ah[i], bh[j], acc[i][j], 0, 0, 0);
                    acc[i][j] = __builtin_amdgcn_mfma_f32_16x16x32_bf16(ah[i], bl[j], acc[i][j], 0, 0, 0);
                    acc[i][j] = __builtin_amdgcn_mfma_f32_16x16x32_bf16(al[i], bh[j], acc[i][j], 0, 0, 0);
                }
        }
        __syncthreads();
    }
    const int mr0 = (w >> 1) * 64, nc0 = (w & 1) * 64;
#pragma unroll
    for (int j = 0; j < 4; ++j) {
        const int col = nb * 128 + nc0 + j * 16 + (l & 15);
        const float bv = bias[col];
#pragma unroll
        for (int i = 0; i < 4; ++i) {
            const int row0 = mb * 128 + mr0 + i * 16 + (l >> 4) * 4;
#pragma unroll
            for (int rg = 0; rg < 4; ++rg)
                C[(size_t)(row0 + rg) * 1536 + col] = acc[i][j][rg] + bv;
        }
    }
}

// ---- Phase 2 tile body: one GRU step for tile (rt, ct). ----
// 16 rows x 16 h-cols x 3 gates, K=512 in BK=64 chunks, split-bf16 MFMA.
// w_hh pre-split (bf16 global); h fp32, split in-register.
__device__ __forceinline__ void gru_tile_body(
    unsigned char* lds,                        // 16 KB
    const float* __restrict__ gi_s,            // [256,1536]
    const unsigned short* __restrict__ whhH,   // bf16 hi [1536,512]
    const unsigned short* __restrict__ whhL,   // bf16 lo
    const float* __restrict__ bhh,             // [1536]
    const float* __restrict__ hold,            // fp32 [256,512]
    float* __restrict__ hnew,                  // fp32 [256,512]
    const int l, const int rt, const int ct)
{
    const int c0 = ct * 16, row0 = rt * 16;
    const int p = l & 7, rb = l >> 3;
    f32x4 acc[3] = {};

    for (int kk = 0; kk < 512; kk += 64) {
#pragma unroll
        for (int i = 0; i < 2; ++i) {          // A: h rows, 16x64, split in-reg
            const int r = i * 8 + rb;
            const int q = p ^ (r & 7);
            const float* g = hold + (size_t)(row0 + r) * 512 + kk + q * 8;
            SV h, lo;
            split8(*(const float4*)g, *(const float4*)(g + 4), h, lo);
            const int o = r * 128 + p * 16;
            *(short8v*)&lds[o] = h.v;
            *(short8v*)&lds[2048 + o] = lo.v;
        }
#pragma unroll
        for (int i = 0; i < 6; ++i) {          // B: 3 gates x 16 cols, 48x64
            const int r = i * 8 + rb;
            const int q = p ^ (r & 7);
            const int wrow = ((r >> 4) << 9) + c0 + (r & 15);
            const size_t g = (size_t)wrow * 512 + kk + q * 8;
            const int o = r * 128 + p * 16;
            *(short8v*)&lds[4096 + o]  = *(const short8v*)(whhH + g);
            *(short8v*)&lds[10240 + o] = *(const short8v*)(whhL + g);
        }
        __syncthreads();
#pragma unroll
        for (int kk2 = 0; kk2 < 2; ++kk2) {
            const int kap = kk2 * 4 + (l >> 4);
            const int arow = l & 15;
            const int aoff = arow * 128 + ((kap ^ (arow & 7)) * 16);
            const short8v ah = *(const short8v*)&lds[aoff];
            const short8v al = *(const short8v*)&lds[2048 + aoff];
#pragma unroll
            for (int j = 0; j < 3; ++j) {
                const int bn = j * 16 + (l & 15);
                const int boff = bn * 128 + ((kap ^ (bn & 7)) * 16);
                const short8v bh = *(const short8v*)&lds[4096 + boff];
                const short8v bl = *(const short8v*)&lds[10240 + boff];
                acc[j] = __builtin_amdgcn_mfma_f32_16x16x32_bf16(ah, bh, acc[j], 0, 0, 0);
                acc[j] = __builtin_amdgcn_mfma_f32_16x16x32_bf16(ah, bl, acc[j], 0, 0, 0);
                acc[j] = __builtin_amdgcn_mfma_f32_16x16x32_bf16(al, bh, acc[j], 0, 0, 0);
            }
        }
        __syncthreads();
    }
    const int col = c0 + (l & 15);
    const float br = bhh[col], bz = bhh[512 + col], bnn = bhh[1024 + col];
#pragma unroll
    for (int rg = 0; rg < 4; ++rg) {
        const int row = row0 + (l >> 4) * 4 + rg;
        const float* gp = gi_s + (size_t)row * 1536 + col;
        const float hv = hold[(size_t)row * 512 + col];
        const float r = sigmoidf_(gp[0]    + acc[0][rg] + br);
        const float z = sigmoidf_(gp[512]  + acc[1][rg] + bz);
        const float n = tanhf(gp[1024] + r * (acc[2][rg] + bnn));
        hnew[(size_t)row * 512 + col] = (1.0f - z) * n + z * hv;
    }
}

// ---- Phase 2a: cooperative persistent kernel — all tc steps, 1 launch. ----
// Grid 512 x 64 thr. Flag-array barrier (gen = absolute step + 1, monotonic;
// flags zeroed once per kernel_launch). Last step skips the barrier.
__global__ __launch_bounds__(64) void gru_coop(
    const float* __restrict__ gi,              // [tc,256,1536] chunk base
    const unsigned short* __restrict__ whhH,
    const unsigned short* __restrict__ whhL,
    const float* __restrict__ bhh,
    float* __restrict__ hA, float* __restrict__ hB,
    unsigned* __restrict__ flags,
    const int t0, const int tc)
{
    __shared__ __attribute__((aligned(16))) unsigned char lds[16384];
    const int l = threadIdx.x;
    const int ct = blockIdx.x & 31;
    const int rt = blockIdx.x >> 5;
    for (int s = 0; s < tc; ++s) {
        const int t = t0 + s;
        const float* hold = (t & 1) ? hB : hA;
        float* hnew = (t & 1) ? hA : hB;
        gru_tile_body(lds, gi + (size_t)s * 256 * 1536, whhH, whhL, bhh,
                      hold, hnew, l, rt, ct);
        if (s + 1 < tc)
            grid_barrier_flags(flags, (unsigned)(t + 1));
    }
}

// ---- Phase 2b: fallback — one step per launch (kernel boundary = barrier).
__global__ __launch_bounds__(64) void gru_step_fb(
    const float* __restrict__ gi_s,
    const unsigned short* __restrict__ whhH,
    const unsigned short* __restrict__ whhL,
    const float* __restrict__ bhh,
    const float* __restrict__ hold, float* __restrict__ hnew)
{
    __shared__ __attribute__((aligned(16))) unsigned char lds[16384];
    gru_tile_body(lds, gi_s, whhH, whhL, bhh, hold, hnew,
                  threadIdx.x, blockIdx.x >> 5, blockIdx.x & 31);
}

// ---- Phase 3 fp32 GEMM (exact; known-good) ----
template<bool TANH>
__global__ __launch_bounds__(256) void gemm_nt_bias(
    const float* __restrict__ A, const float* __restrict__ B,
    const float* __restrict__ bias, float* __restrict__ C,
    const int N, const int K)
{
    __shared__ float As[32][68];
    __shared__ float Bs[32][68];
    const int nb = blockIdx.x, mb = blockIdx.y;
    const int t  = threadIdx.x;
    const int tx = t & 15, ty = t >> 4;
    const int lr = t >> 3;
    const int lk = (t & 7) << 2;
    const float* pA = A + (size_t)(mb * 64 + lr) * K + lk;
    const float* pB = B + (size_t)(nb * 64 + lr) * K + lk;
    float acc[4][4];
#pragma unroll
    for (int i = 0; i < 4; ++i)
#pragma unroll
        for (int j = 0; j < 4; ++j) acc[i][j] = 0.0f;
    for (int kk = 0; kk < K; kk += 32) {
        const float4 a0 = *(const float4*)(pA + kk);
        const float4 a1 = *(const float4*)(pA + (size_t)32 * K + kk);
        const float4 b0 = *(const float4*)(pB + kk);
        const float4 b1 = *(const float4*)(pB + (size_t)32 * K + kk);
        __syncthreads();
        As[lk+0][lr] = a0.x; As[lk+1][lr] = a0.y; As[lk+2][lr] = a0.z; As[lk+3][lr] = a0.w;
        As[lk+0][lr+32] = a1.x; As[lk+1][lr+32] = a1.y; As[lk+2][lr+32] = a1.z; As[lk+3][lr+32] = a1.w;
        Bs[lk+0][lr] = b0.x; Bs[lk+1][lr] = b0.y; Bs[lk+2][lr] = b0.z; Bs[lk+3][lr] = b0.w;
        Bs[lk+0][lr+32] = b1.x; Bs[lk+1][lr+32] = b1.y; Bs[lk+2][lr+32] = b1.z; Bs[lk+3][lr+32] = b1.w;
        __syncthreads();
#pragma unroll
        for (int k = 0; k < 32; ++k) {
            const float4 av = *(const float4*)&As[k][ty << 2];
            const float4 bv = *(const float4*)&Bs[k][tx << 2];
            acc[0][0] += av.x * bv.x; acc[0][1] += av.x * bv.y; acc[0][2] += av.x * bv.z; acc[0][3] += av.x * bv.w;
            acc[1][0] += av.y * bv.x; acc[1][1] += av.y * bv.y; acc[1][2] += av.y * bv.z; acc[1][3] += av.y * bv.w;
            acc[2][0] += av.z * bv.x; acc[2][1] += av.z * bv.y; acc[2][2] += av.z * bv.z; acc[2][3] += av.z * bv.w;
            acc[3][0] += av.w * bv.x; acc[3][1] += av.w * bv.y; acc[3][2] += av.w * bv.z; acc[3][3] += av.w * bv.w;
        }
    }
    const int crow = mb * 64 + (ty << 2);
    const int ccol = nb * 64 + (tx << 2);
    const float4 bv = *(const float4*)(bias + ccol);
#pragma unroll
    for (int i = 0; i < 4; ++i) {
        float4 o;
        o.x = acc[i][0] + bv.x; o.y = acc[i][1] + bv.y;
        o.z = acc[i][2] + bv.z; o.w = acc[i][3] + bv.w;
        if (TANH) { o.x = tanhf(o.x); o.y = tanhf(o.y); o.z = tanhf(o.z); o.w = tanhf(o.w); }
        *(float4*)(C + (size_t)(crow + i) * N + ccol) = o;
    }
}

__global__ __launch_bounds__(256) void value_head(
    const float* __restrict__ out1, const float* __restrict__ W2,
    const float* __restrict__ b2, float* __restrict__ out)
{
    const int b = blockIdx.x, t = threadIdx.x;
    float p = out1[(size_t)b * 512 + t] * W2[t]
            + out1[(size_t)b * 512 + 256 + t] * W2[256 + t];
#pragma unroll
    for (int off = 32; off > 0; off >>= 1) p += __shfl_down(p, off, 64);
    __shared__ float ps[4];
    if ((t & 63) == 0) ps[t >> 6] = p;
    __syncthreads();
    if (t == 0) out[b] = tanhf(ps[0] + ps[1] + ps[2] + ps[3] + b2[0]);
}

extern "C" void kernel_launch(void* const* d_in, const int* in_sizes, int n_in,
                              void* d_out, int out_size, void* d_ws, size_t ws_size,
                              hipStream_t stream)
{
    (void)in_sizes; (void)n_in; (void)out_size;
    const float* input = (const float*)d_in[0];   // [256,256,512]
    const float* w_ih  = (const float*)d_in[1];   // [1536,512]
    const float* w_hh  = (const float*)d_in[2];   // [1536,512]
    const float* b_ih  = (const float*)d_in[3];   // [1536]
    const float* b_hh  = (const float*)d_in[4];   // [1536]
    const float* W1    = (const float*)d_in[5];   // [512,512]
    const float* b1    = (const float*)d_in[6];   // [512]
    const float* W2    = (const float*)d_in[7];   // [512]
    const float* b2    = (const float*)d_in[8];   // [1]
    float* out = (float*)d_out;
    float* ws  = (float*)d_ws;

    // ws layout in FLOAT SLOTS. One [1536,512] bf16 buffer = 786432 ushorts
    // = 1,572,864 B = 393,216 float slots.
    float* hA = ws;                                        // [0, 131072)
    float* hB = ws + 131072;                               // [131072, 262144)
    float* o1 = ws + 262144;                               // [262144, 393216)
    unsigned short* wihH = (unsigned short*)(ws + 393216); // [393216, 786432)
    unsigned short* wihL = (unsigned short*)(ws + 786432); // [786432, 1179648)
    unsigned short* whhH = (unsigned short*)(ws + 1179648);// [1179648, 1572864)
    unsigned short* whhL = (unsigned short*)(ws + 1572864);// [1572864, 1966080)
    unsigned* flags = (unsigned*)(ws + 1966080);           // [1966080, 1966592) 512 u32
    float* gi = ws + 1966592;

    const size_t per_step = 256 * 1536;             // gi floats per timestep
    const size_t base = 1966592;
    const size_t avail = (ws_size / 4 > base) ? ws_size / 4 - base : 0;
    int Tc = (int)(avail / per_step);
    if (Tc > 256) Tc = 256;
    if (Tc < 1) Tc = 1;

    hipMemsetAsync(hA, 0, 131072 * sizeof(float), stream);    // h(-1) = 0
    hipMemsetAsync(flags, 0, 512 * sizeof(unsigned), stream); // barrier gen 0

    cast_split<<<768, 256, 0, stream>>>(w_ih, wihH, wihL, 196608);
    cast_split<<<768, 256, 0, stream>>>(w_hh, whhH, whhL, 196608);

    for (int t0 = 0; t0 < 256; t0 += Tc) {
        const int tc = (t0 + Tc <= 256) ? Tc : (256 - t0);
        const int Mc = tc * 256;
        // Phase 1 (chunk): gi = X_chunk @ w_ih^T + b_ih
        gemm_gi_mfma<<<dim3(12, Mc / 128), 256, 0, stream>>>(
            input + (size_t)t0 * 256 * 512, wihH, wihL, b_ih, gi);
        // Phase 2 (chunk): coop persistent kernel + flag-array barrier.
        {
            const float* a_gi = gi;
            const unsigned short* a_wh = whhH; const unsigned short* a_wl = whhL;
            const float* a_bh = b_hh;
            float* a_hA = hA; float* a_hB = hB;
            unsigned* a_fl = flags;
            int a_t0 = t0; int a_tc = tc;
            void* args[] = {&a_gi, &a_wh, &a_wl, &a_bh, &a_hA, &a_hB, &a_fl, &a_t0, &a_tc};
            hipError_t rc = hipLaunchCooperativeKernel(
                (const void*)gru_coop, dim3(512), dim3(64), args, 0, stream);
            if (rc != hipSuccess) {
                // Fallback: per-step launches (kernel boundary = grid barrier)
                for (int s = 0; s < tc; ++s) {
                    const int t = t0 + s;
                    const float* hold = (t & 1) ? hB : hA;
                    float* hnew = (t & 1) ? hA : hB;
                    gru_step_fb<<<dim3(512), 64, 0, stream>>>(
                        gi + (size_t)s * per_step, whhH, whhL, b_hh, hold, hnew);
                }
            }
        }
    }

    // Phase 3: final h is in hA (after 256 steps, even count).
    gemm_nt_bias<true><<<dim3(512 / 64, 256 / 64), 256, 0, stream>>>(
        hA, W1, b1, o1, 512, 512);
    value_head<<<256, 256, 0, stream>>>(o1, W2, b2, out);
}

// Round 9
// 6398.276 us; speedup vs baseline: 3.2015x; 1.7643x over previous
//
#include <hip/hip_runtime.h>
#include <hip/hip_bf16.h>

typedef __attribute__((ext_vector_type(8))) short short8v;   // 8 bf16 = 16 B
typedef __attribute__((ext_vector_type(4))) float f32x4;

union SV { short8v v; unsigned short u[8]; };
union FU { float f; unsigned u; };
union QF { unsigned long long q[4]; float4 v[2]; };

// Truncation split: x ~= hi + lo, residual <= 2^-16 |x|.
__device__ __forceinline__ void split2(float x, unsigned short& hi, unsigned short& lo) {
    FU a; a.f = x;
    hi = (unsigned short)(a.u >> 16);
    FU h; h.u = a.u & 0xffff0000u;
    FU r; r.f = x - h.f;              // exact
    lo = (unsigned short)(r.u >> 16);
}
__device__ __forceinline__ void split8(const float4 a0, const float4 a1, SV& h, SV& l) {
    split2(a0.x, h.u[0], l.u[0]); split2(a0.y, h.u[1], l.u[1]);
    split2(a0.z, h.u[2], l.u[2]); split2(a0.w, h.u[3], l.u[3]);
    split2(a1.x, h.u[4], l.u[4]); split2(a1.y, h.u[5], l.u[5]);
    split2(a1.z, h.u[6], l.u[6]); split2(a1.w, h.u[7], l.u[7]);
}
__device__ __forceinline__ float sigmoidf_(float x) {
    return 1.0f / (1.0f + __expf(-x));
}

// Agent-scope (LLC-coherent, L2-bypassing) h accessors. All cross-step h
// traffic goes through these -> no dirty h in L2 -> no wbl2/inv fences needed.
__device__ __forceinline__ unsigned long long h_load64(const float* p) {
    return __hip_atomic_load((const unsigned long long*)p,
                             __ATOMIC_RELAXED, __HIP_MEMORY_SCOPE_AGENT);
}
__device__ __forceinline__ float h_load32(const float* p) {
    FU u; u.u = __hip_atomic_load((const unsigned*)p,
                                  __ATOMIC_RELAXED, __HIP_MEMORY_SCOPE_AGENT);
    return u.f;
}
__device__ __forceinline__ void h_store32(float* p, float v) {
    FU u; u.f = v;
    __hip_atomic_store((unsigned*)p, u.u,
                       __ATOMIC_RELAXED, __HIP_MEMORY_SCOPE_AGENT);
}

// Per-rt-group barrier (32 blocks). R8's global version cost ~38us/step:
// 512 waves polling one 4KB region + per-step wbl2/inv (which also evicted
// w_hh/gi from L2). Here: group = the 32 blocks sharing rt (the exact h-row
// writer set each block reads). Arrive = s_waitcnt(0) [h atomics are at LLC]
// + one scoped flag store. Wait = lanes 0..15 poll 16 u64 (2 lines/group).
// No cache-maintenance fences anywhere; gen monotonic; flags zeroed per
// kernel_launch (replay-safe). Blocks are 1 wave.
__device__ __forceinline__ void group_barrier(unsigned* gf, const int ct, const unsigned gen) {
    __syncthreads();
    __builtin_amdgcn_s_waitcnt(0);       // wave's h-stores committed at LLC
    __atomic_signal_fence(__ATOMIC_SEQ_CST);
    if (threadIdx.x == 0)
        __hip_atomic_store(&gf[ct], gen,
                           __ATOMIC_RELAXED, __HIP_MEMORY_SCOPE_AGENT);
    if (threadIdx.x < 16) {
        const unsigned long long* f64 = (const unsigned long long*)gf;
        for (;;) {
            unsigned long long v = __hip_atomic_load(
                &f64[threadIdx.x], __ATOMIC_RELAXED, __HIP_MEMORY_SCOPE_AGENT);
            if (((unsigned)v >= gen) && ((unsigned)(v >> 32) >= gen)) break;
            __builtin_amdgcn_s_sleep(1);
        }
    }
    __atomic_signal_fence(__ATOMIC_SEQ_CST);
    __syncthreads();
}

// ---- split-cast weights f32 -> (hi, lo) bf16, once ----
__global__ __launch_bounds__(256) void cast_split(
    const float* __restrict__ in, unsigned short* __restrict__ hi,
    unsigned short* __restrict__ lo, int n4)
{
    int i = blockIdx.x * 256 + threadIdx.x;
    if (i < n4) {
        float4 v = ((const float4*)in)[i];
        ushort4 h, l;
        split2(v.x, h.x, l.x); split2(v.y, h.y, l.y);
        split2(v.z, h.z, l.z); split2(v.w, h.w, l.w);
        ((ushort4*)hi)[i] = h;
        ((ushort4*)lo)[i] = l;
    }
}

// ---- Phase 1: gi = X @ w_ih^T + b_ih. Split-bf16 MFMA (3 products). ----
// 128x128 tile, BK=64, 256 thr (4 waves, 2x2 quadrants). A (X) split
// in-register; B (w_ih) pre-split global bf16. Linear LDS writes with
// pre-swizzled k-slot; XOR-swizzled b128 reads (<=2-way, free).
__global__ __launch_bounds__(256, 2) void gemm_gi_mfma(
    const float* __restrict__ A,            // [M,512] fp32
    const unsigned short* __restrict__ Bh,  // [1536,512] bf16 hi
    const unsigned short* __restrict__ Bl,  // [1536,512] bf16 lo
    const float* __restrict__ bias,         // [1536]
    float* __restrict__ C)                  // [M,1536]
{
    __shared__ __attribute__((aligned(16))) unsigned char lds[65536];
    // A_hi[0,16K) A_lo[16K,32K) B_hi[32K,48K) B_lo[48K,64K)
    const int t = threadIdx.x;
    const int l = t & 63, w = t >> 6;
    const int nb = blockIdx.x, mb = blockIdx.y;
    const int p = t & 7;
    const int rbase = t >> 3;
    f32x4 acc[4][4] = {};

    for (int kk = 0; kk < 512; kk += 64) {
#pragma unroll
        for (int i = 0; i < 4; ++i) {
            const int r = i * 32 + rbase;            // tile row 0..127
            const int q = p ^ (r & 7);               // pre-swizzled k-slot
            const float* ga = A + (size_t)(mb * 128 + r) * 512 + kk + q * 8;
            SV ah, al;
            split8(*(const float4*)ga, *(const float4*)(ga + 4), ah, al);
            const int o = r * 128 + p * 16;
            *(short8v*)&lds[o] = ah.v;
            *(short8v*)&lds[16384 + o] = al.v;
            const size_t gb = (size_t)(nb * 128 + r) * 512 + kk + q * 8;
            *(short8v*)&lds[32768 + o] = *(const short8v*)(Bh + gb);
            *(short8v*)&lds[49152 + o] = *(const short8v*)(Bl + gb);
        }
        __syncthreads();
        const int mr0 = (w >> 1) * 64, nc0 = (w & 1) * 64;
#pragma unroll
        for (int kk2 = 0; kk2 < 2; ++kk2) {
            const int kap = kk2 * 4 + (l >> 4);
            short8v ah[4], al[4], bh[4], bl[4];
#pragma unroll
            for (int i = 0; i < 4; ++i) {
                const int row = mr0 + i * 16 + (l & 15);
                const int off = row * 128 + ((kap ^ (row & 7)) * 16);
                ah[i] = *(const short8v*)&lds[off];
                al[i] = *(const short8v*)&lds[16384 + off];
            }
#pragma unroll
            for (int j = 0; j < 4; ++j) {
                const int bn = nc0 + j * 16 + (l & 15);
                const int off = bn * 128 + ((kap ^ (bn & 7)) * 16);
                bh[j] = *(const short8v*)&lds[32768 + off];
                bl[j] = *(const short8v*)&lds[49152 + off];
            }
#pragma unroll
            for (int i = 0; i < 4; ++i)
#pragma unroll
                for (int j = 0; j < 4; ++j) {
                    acc[i][j] = __builtin_amdgcn_mfma_f32_16x16x32_bf16(ah[i], bh[j], acc[i][j], 0, 0, 0);
                    acc[i][j] = __builtin_amdgcn_mfma_f32_16x16x32_bf16(ah[i], bl[j], acc[i][j], 0, 0, 0);
                    acc[i][j] = __builtin_amdgcn_mfma_f32_16x16x32_bf16(al[i], bh[j], acc[i][j], 0, 0, 0);
                }
        }
        __syncthreads();
    }
    const int mr0 = (w >> 1) * 64, nc0 = (w & 1) * 64;
#pragma unroll
    for (int j = 0; j < 4; ++j) {
        const int col = nb * 128 + nc0 + j * 16 + (l & 15);
        const float bv = bias[col];
#pragma unroll
        for (int i = 0; i < 4; ++i) {
            const int row0 = mb * 128 + mr0 + i * 16 + (l >> 4) * 4;
#pragma unroll
            for (int rg = 0; rg < 4; ++rg)
                C[(size_t)(row0 + rg) * 1536 + col] = acc[i][j][rg] + bv;
        }
    }
}

// ---- Phase 2 tile body: one GRU step for tile (rt, ct). ----
// 16 rows x 16 h-cols x 3 gates, K=512 in BK=64 chunks, split-bf16 MFMA.
// w_hh pre-split bf16 (normal loads, stays L2-hot — no invalidates);
// h fp32 via agent-scope atomics only (LLC-coherent, L2-bypassed).
__device__ __forceinline__ void gru_tile_body(
    unsigned char* lds,                        // 16 KB
    const float* __restrict__ gi_s,            // [256,1536]
    const unsigned short* __restrict__ whhH,   // bf16 hi [1536,512]
    const unsigned short* __restrict__ whhL,   // bf16 lo
    const float* __restrict__ bhh,             // [1536]
    const float* __restrict__ hold,            // fp32 [256,512]
    float* __restrict__ hnew,                  // fp32 [256,512]
    const int l, const int rt, const int ct)
{
    const int c0 = ct * 16, row0 = rt * 16;
    const int p = l & 7, rb = l >> 3;
    f32x4 acc[3] = {};

    for (int kk = 0; kk < 512; kk += 64) {
#pragma unroll
        for (int i = 0; i < 2; ++i) {          // A: h rows 16x64, atomic loads
            const int r = i * 8 + rb;
            const int q = p ^ (r & 7);
            const float* g = hold + (size_t)(row0 + r) * 512 + kk + q * 8;
            QF buf;
#pragma unroll
            for (int j = 0; j < 4; ++j) buf.q[j] = h_load64(g + j * 2);
            SV h, lo;
            split8(buf.v[0], buf.v[1], h, lo);
            const int o = r * 128 + p * 16;
            *(short8v*)&lds[o] = h.v;
            *(short8v*)&lds[2048 + o] = lo.v;
        }
#pragma unroll
        for (int i = 0; i < 6; ++i) {          // B: 3 gates x 16 cols, 48x64
            const int r = i * 8 + rb;
            const int q = p ^ (r & 7);
            const int wrow = ((r >> 4) << 9) + c0 + (r & 15);
            const size_t g = (size_t)wrow * 512 + kk + q * 8;
            const int o = r * 128 + p * 16;
            *(short8v*)&lds[4096 + o]  = *(const short8v*)(whhH + g);
            *(short8v*)&lds[10240 + o] = *(const short8v*)(whhL + g);
        }
        __syncthreads();
#pragma unroll
        for (int kk2 = 0; kk2 < 2; ++kk2) {
            const int kap = kk2 * 4 + (l >> 4);
            const int arow = l & 15;
            const int aoff = arow * 128 + ((kap ^ (arow & 7)) * 16);
            const short8v ah = *(const short8v*)&lds[aoff];
            const short8v al = *(const short8v*)&lds[2048 + aoff];
#pragma unroll
            for (int j = 0; j < 3; ++j) {
                const int bn = j * 16 + (l & 15);
                const int boff = bn * 128 + ((kap ^ (bn & 7)) * 16);
                const short8v bh = *(const short8v*)&lds[4096 + boff];
                const short8v bl = *(const short8v*)&lds[10240 + boff];
                acc[j] = __builtin_amdgcn_mfma_f32_16x16x32_bf16(ah, bh, acc[j], 0, 0, 0);
                acc[j] = __builtin_amdgcn_mfma_f32_16x16x32_bf16(ah, bl, acc[j], 0, 0, 0);
                acc[j] = __builtin_amdgcn_mfma_f32_16x16x32_bf16(al, bh, acc[j], 0, 0, 0);
            }
        }
        __syncthreads();
    }
    const int col = c0 + (l & 15);
    const float br = bhh[col], bz = bhh[512 + col], bnn = bhh[1024 + col];
#pragma unroll
    for (int rg = 0; rg < 4; ++rg) {
        const int row = row0 + (l >> 4) * 4 + rg;
        const float* gp = gi_s + (size_t)row * 1536 + col;
        const float hv = h_load32(hold + (size_t)row * 512 + col);
        const float r = sigmoidf_(gp[0]    + acc[0][rg] + br);
        const float z = sigmoidf_(gp[512]  + acc[1][rg] + bz);
        const float n = tanhf(gp[1024] + r * (acc[2][rg] + bnn));
        h_store32(hnew + (size_t)row * 512 + col, (1.0f - z) * n + z * hv);
    }
}

// ---- Phase 2a: cooperative persistent kernel — all tc steps, 1 launch. ----
// Grid 512 x 64 thr. Per-rt-group barrier (32 blocks each; the exact h
// dependency set). gen = absolute step + 1 (monotonic across chunk launches;
// skipped gens at chunk edges are fine under >= compare). Last step of a
// chunk skips the barrier (kernel end is the release point).
__global__ __launch_bounds__(64) void gru_coop(
    const float* __restrict__ gi,              // [tc,256,1536] chunk base
    const unsigned short* __restrict__ whhH,
    const unsigned short* __restrict__ whhL,
    const float* __restrict__ bhh,
    float* __restrict__ hA, float* __restrict__ hB,
    unsigned* __restrict__ flags,              // 16 groups x 32 u32
    const int t0, const int tc)
{
    __shared__ __attribute__((aligned(16))) unsigned char lds[16384];
    const int l = threadIdx.x;
    const int ct = blockIdx.x & 31;
    const int rt = blockIdx.x >> 5;
    unsigned* gf = flags + rt * 32;
    for (int s = 0; s < tc; ++s) {
        const int t = t0 + s;
        const float* hold = (t & 1) ? hB : hA;
        float* hnew = (t & 1) ? hA : hB;
        gru_tile_body(lds, gi + (size_t)s * 256 * 1536, whhH, whhL, bhh,
                      hold, hnew, l, rt, ct);
        if (s + 1 < tc)
            group_barrier(gf, ct, (unsigned)(t + 1));
    }
}

// ---- Phase 2b: fallback — one step per launch (kernel boundary = barrier).
__global__ __launch_bounds__(64) void gru_step_fb(
    const float* __restrict__ gi_s,
    const unsigned short* __restrict__ whhH,
    const unsigned short* __restrict__ whhL,
    const float* __restrict__ bhh,
    const float* __restrict__ hold, float* __restrict__ hnew)
{
    __shared__ __attribute__((aligned(16))) unsigned char lds[16384];
    gru_tile_body(lds, gi_s, whhH, whhL, bhh, hold, hnew,
                  threadIdx.x, blockIdx.x >> 5, blockIdx.x & 31);
}

// ---- Phase 3 fp32 GEMM (exact; known-good) ----
template<bool TANH>
__global__ __launch_bounds__(256) void gemm_nt_bias(
    const float* __restrict__ A, const float* __restrict__ B,
    const float* __restrict__ bias, float* __restrict__ C,
    const int N, const int K)
{
    __shared__ float As[32][68];
    __shared__ float Bs[32][68];
    const int nb = blockIdx.x, mb = blockIdx.y;
    const int t  = threadIdx.x;
    const int tx = t & 15, ty = t >> 4;
    const int lr = t >> 3;
    const int lk = (t & 7) << 2;
    const float* pA = A + (size_t)(mb * 64 + lr) * K + lk;
    const float* pB = B + (size_t)(nb * 64 + lr) * K + lk;
    float acc[4][4];
#pragma unroll
    for (int i = 0; i < 4; ++i)
#pragma unroll
        for (int j = 0; j < 4; ++j) acc[i][j] = 0.0f;
    for (int kk = 0; kk < K; kk += 32) {
        const float4 a0 = *(const float4*)(pA + kk);
        const float4 a1 = *(const float4*)(pA + (size_t)32 * K + kk);
        const float4 b0 = *(const float4*)(pB + kk);
        const float4 b1 = *(const float4*)(pB + (size_t)32 * K + kk);
        __syncthreads();
        As[lk+0][lr] = a0.x; As[lk+1][lr] = a0.y; As[lk+2][lr] = a0.z; As[lk+3][lr] = a0.w;
        As[lk+0][lr+32] = a1.x; As[lk+1][lr+32] = a1.y; As[lk+2][lr+32] = a1.z; As[lk+3][lr+32] = a1.w;
        Bs[lk+0][lr] = b0.x; Bs[lk+1][lr] = b0.y; Bs[lk+2][lr] = b0.z; Bs[lk+3][lr] = b0.w;
        Bs[lk+0][lr+32] = b1.x; Bs[lk+1][lr+32] = b1.y; Bs[lk+2][lr+32] = b1.z; Bs[lk+3][lr+32] = b1.w;
        __syncthreads();
#pragma unroll
        for (int k = 0; k < 32; ++k) {
            const float4 av = *(const float4*)&As[k][ty << 2];
            const float4 bv = *(const float4*)&Bs[k][tx << 2];
            acc[0][0] += av.x * bv.x; acc[0][1] += av.x * bv.y; acc[0][2] += av.x * bv.z; acc[0][3] += av.x * bv.w;
            acc[1][0] += av.y * bv.x; acc[1][1] += av.y * bv.y; acc[1][2] += av.y * bv.z; acc[1][3] += av.y * bv.w;
            acc[2][0] += av.z * bv.x; acc[2][1] += av.z * bv.y; acc[2][2] += av.z * bv.z; acc[2][3] += av.z * bv.w;
            acc[3][0] += av.w * bv.x; acc[3][1] += av.w * bv.y; acc[3][2] += av.w * bv.z; acc[3][3] += av.w * bv.w;
        }
    }
    const int crow = mb * 64 + (ty << 2);
    const int ccol = nb * 64 + (tx << 2);
    const float4 bv = *(const float4*)(bias + ccol);
#pragma unroll
    for (int i = 0; i < 4; ++i) {
        float4 o;
        o.x = acc[i][0] + bv.x; o.y = acc[i][1] + bv.y;
        o.z = acc[i][2] + bv.z; o.w = acc[i][3] + bv.w;
        if (TANH) { o.x = tanhf(o.x); o.y = tanhf(o.y); o.z = tanhf(o.z); o.w = tanhf(o.w); }
        *(float4*)(C + (size_t)(crow + i) * N + ccol) = o;
    }
}

__global__ __launch_bounds__(256) void value_head(
    const float* __restrict__ out1, const float* __restrict__ W2,
    const float* __restrict__ b2, float* __restrict__ out)
{
    const int b = blockIdx.x, t = threadIdx.x;
    float p = out1[(size_t)b * 512 + t] * W2[t]
            + out1[(size_t)b * 512 + 256 + t] * W2[256 + t];
#pragma unroll
    for (int off = 32; off > 0; off >>= 1) p += __shfl_down(p, off, 64);
    __shared__ float ps[4];
    if ((t & 63) == 0) ps[t >> 6] = p;
    __syncthreads();
    if (t == 0) out[b] = tanhf(ps[0] + ps[1] + ps[2] + ps[3] + b2[0]);
}

extern "C" void kernel_launch(void* const* d_in, const int* in_sizes, int n_in,
                              void* d_out, int out_size, void* d_ws, size_t ws_size,
                              hipStream_t stream)
{
    (void)in_sizes; (void)n_in; (void)out_size;
    const float* input = (const float*)d_in[0];   // [256,256,512]
    const float* w_ih  = (const float*)d_in[1];   // [1536,512]
    const float* w_hh  = (const float*)d_in[2];   // [1536,512]
    const float* b_ih  = (const float*)d_in[3];   // [1536]
    const float* b_hh  = (const float*)d_in[4];   // [1536]
    const float* W1    = (const float*)d_in[5];   // [512,512]
    const float* b1    = (const float*)d_in[6];   // [512]
    const float* W2    = (const float*)d_in[7];   // [512]
    const float* b2    = (const float*)d_in[8];   // [1]
    float* out = (float*)d_out;
    float* ws  = (float*)d_ws;

    // ws layout in FLOAT SLOTS. One [1536,512] bf16 buffer = 786432 ushorts
    // = 1,572,864 B = 393,216 float slots.
    float* hA = ws;                                        // [0, 131072)
    float* hB = ws + 131072;                               // [131072, 262144)
    float* o1 = ws + 262144;                               // [262144, 393216)
    unsigned short* wihH = (unsigned short*)(ws + 393216); // [393216, 786432)
    unsigned short* wihL = (unsigned short*)(ws + 786432); // [786432, 1179648)
    unsigned short* whhH = (unsigned short*)(ws + 1179648);// [1179648, 1572864)
    unsigned short* whhL = (unsigned short*)(ws + 1572864);// [1572864, 1966080)
    unsigned* flags = (unsigned*)(ws + 1966080);           // [1966080, 1966592) 512 u32
    float* gi = ws + 1966592;

    const size_t per_step = 256 * 1536;             // gi floats per timestep
    const size_t base = 1966592;
    const size_t avail = (ws_size / 4 > base) ? ws_size / 4 - base : 0;
    int Tc = (int)(avail / per_step);
    if (Tc > 256) Tc = 256;
    if (Tc < 1) Tc = 1;

    hipMemsetAsync(hA, 0, 131072 * sizeof(float), stream);    // h(-1) = 0
    hipMemsetAsync(flags, 0, 512 * sizeof(unsigned), stream); // barrier gen 0

    cast_split<<<768, 256, 0, stream>>>(w_ih, wihH, wihL, 196608);
    cast_split<<<768, 256, 0, stream>>>(w_hh, whhH, whhL, 196608);

    for (int t0 = 0; t0 < 256; t0 += Tc) {
        const int tc = (t0 + Tc <= 256) ? Tc : (256 - t0);
        const int Mc = tc * 256;
        // Phase 1 (chunk): gi = X_chunk @ w_ih^T + b_ih
        gemm_gi_mfma<<<dim3(12, Mc / 128), 256, 0, stream>>>(
            input + (size_t)t0 * 256 * 512, wihH, wihL, b_ih, gi);
        // Phase 2 (chunk): coop persistent kernel + per-group barrier.
        {
            const float* a_gi = gi;
            const unsigned short* a_wh = whhH; const unsigned short* a_wl = whhL;
            const float* a_bh = b_hh;
            float* a_hA = hA; float* a_hB = hB;
            unsigned* a_fl = flags;
            int a_t0 = t0; int a_tc = tc;
            void* args[] = {&a_gi, &a_wh, &a_wl, &a_bh, &a_hA, &a_hB, &a_fl, &a_t0, &a_tc};
            hipError_t rc = hipLaunchCooperativeKernel(
                (const void*)gru_coop, dim3(512), dim3(64), args, 0, stream);
            if (rc != hipSuccess) {
                // Fallback: per-step launches (kernel boundary = grid barrier)
                for (int s = 0; s < tc; ++s) {
                    const int t = t0 + s;
                    const float* hold = (t & 1) ? hB : hA;
                    float* hnew = (t & 1) ? hA : hB;
                    gru_step_fb<<<dim3(512), 64, 0, stream>>>(
                        gi + (size_t)s * per_step, whhH, whhL, b_hh, hold, hnew);
                }
            }
        }
    }

    // Phase 3: final h is in hA (after 256 steps, even count).
    gemm_nt_bias<true><<<dim3(512 / 64, 256 / 64), 256, 0, stream>>>(
        hA, W1, b1, o1, 512, 512);
    value_head<<<256, 256, 0, stream>>>(o1, W2, b2, out);
}

// Round 10
// 2476.022 us; speedup vs baseline: 8.2731x; 2.5841x over previous
//
#include <hip/hip_runtime.h>
#include <hip/hip_bf16.h>

typedef __attribute__((ext_vector_type(8))) short short8v;   // 8 bf16 = 16 B
typedef __attribute__((ext_vector_type(4))) float f32x4;

union SV { short8v v; unsigned short u[8]; };
union FU { float f; unsigned u; };
union QF { unsigned long long q[4]; float4 v[2]; };

// Truncation split: x ~= hi + lo, residual <= 2^-16 |x|.
__device__ __forceinline__ void split2(float x, unsigned short& hi, unsigned short& lo) {
    FU a; a.f = x;
    hi = (unsigned short)(a.u >> 16);
    FU h; h.u = a.u & 0xffff0000u;
    FU r; r.f = x - h.f;              // exact
    lo = (unsigned short)(r.u >> 16);
}
__device__ __forceinline__ void split8(const float4 a0, const float4 a1, SV& h, SV& l) {
    split2(a0.x, h.u[0], l.u[0]); split2(a0.y, h.u[1], l.u[1]);
    split2(a0.z, h.u[2], l.u[2]); split2(a0.w, h.u[3], l.u[3]);
    split2(a1.x, h.u[4], l.u[4]); split2(a1.y, h.u[5], l.u[5]);
    split2(a1.z, h.u[6], l.u[6]); split2(a1.w, h.u[7], l.u[7]);
}
__device__ __forceinline__ float sigmoidf_(float x) {
    return 1.0f / (1.0f + __expf(-x));
}

// Agent-scope (LLC-coherent, L2-bypassing) h accessors — all cross-step h
// traffic, so no cache-maintenance fences are needed anywhere.
__device__ __forceinline__ unsigned long long h_load64(const float* p) {
    return __hip_atomic_load((const unsigned long long*)p,
                             __ATOMIC_RELAXED, __HIP_MEMORY_SCOPE_AGENT);
}
__device__ __forceinline__ float h_load32(const float* p) {
    FU u; u.u = __hip_atomic_load((const unsigned*)p,
                                  __ATOMIC_RELAXED, __HIP_MEMORY_SCOPE_AGENT);
    return u.f;
}
__device__ __forceinline__ void h_store32(float* p, float v) {
    FU u; u.f = v;
    __hip_atomic_store((unsigned*)p, u.u,
                       __ATOMIC_RELAXED, __HIP_MEMORY_SCOPE_AGENT);
}

// Per-rt-group barrier (32 blocks x 4 waves). Arrive: per-wave s_waitcnt(0)
// (h atomic-stores committed at LLC) -> __syncthreads (all waves done) ->
// wave-0 lane-0 scoped flag store. Wait: lanes 0..15 poll 16 u64. gen is
// monotonic; flags zeroed once per kernel_launch (replay-safe).
__device__ __forceinline__ void group_barrier(unsigned* gf, const int ct,
                                              const unsigned gen) {
    __builtin_amdgcn_s_waitcnt(0);
    __syncthreads();
    __atomic_signal_fence(__ATOMIC_SEQ_CST);
    if (threadIdx.x == 0)
        __hip_atomic_store(&gf[ct], gen,
                           __ATOMIC_RELAXED, __HIP_MEMORY_SCOPE_AGENT);
    if (threadIdx.x < 16) {
        const unsigned long long* f64 = (const unsigned long long*)gf;
        for (;;) {
            unsigned long long v = __hip_atomic_load(
                &f64[threadIdx.x], __ATOMIC_RELAXED, __HIP_MEMORY_SCOPE_AGENT);
            if (((unsigned)v >= gen) && ((unsigned)(v >> 32) >= gen)) break;
            __builtin_amdgcn_s_sleep(1);
        }
    }
    __atomic_signal_fence(__ATOMIC_SEQ_CST);
    __syncthreads();
}

// ---- split-cast weights f32 -> (hi, lo) bf16, once ----
__global__ __launch_bounds__(256) void cast_split(
    const float* __restrict__ in, unsigned short* __restrict__ hi,
    unsigned short* __restrict__ lo, int n4)
{
    int i = blockIdx.x * 256 + threadIdx.x;
    if (i < n4) {
        float4 v = ((const float4*)in)[i];
        ushort4 h, l;
        split2(v.x, h.x, l.x); split2(v.y, h.y, l.y);
        split2(v.z, h.z, l.z); split2(v.w, h.w, l.w);
        ((ushort4*)hi)[i] = h;
        ((ushort4*)lo)[i] = l;
    }
}

// ---- Phase 1: gi = X @ w_ih^T + b_ih. Split-bf16 MFMA (3 products). ----
// (unchanged from R9 — ~200us, not the bottleneck)
__global__ __launch_bounds__(256, 2) void gemm_gi_mfma(
    const float* __restrict__ A,            // [M,512] fp32
    const unsigned short* __restrict__ Bh,  // [1536,512] bf16 hi
    const unsigned short* __restrict__ Bl,  // [1536,512] bf16 lo
    const float* __restrict__ bias,         // [1536]
    float* __restrict__ C)                  // [M,1536]
{
    __shared__ __attribute__((aligned(16))) unsigned char lds[65536];
    const int t = threadIdx.x;
    const int l = t & 63, w = t >> 6;
    const int nb = blockIdx.x, mb = blockIdx.y;
    const int p = t & 7;
    const int rbase = t >> 3;
    f32x4 acc[4][4] = {};

    for (int kk = 0; kk < 512; kk += 64) {
#pragma unroll
        for (int i = 0; i < 4; ++i) {
            const int r = i * 32 + rbase;
            const int q = p ^ (r & 7);
            const float* ga = A + (size_t)(mb * 128 + r) * 512 + kk + q * 8;
            SV ah, al;
            split8(*(const float4*)ga, *(const float4*)(ga + 4), ah, al);
            const int o = r * 128 + p * 16;
            *(short8v*)&lds[o] = ah.v;
            *(short8v*)&lds[16384 + o] = al.v;
            const size_t gb = (size_t)(nb * 128 + r) * 512 + kk + q * 8;
            *(short8v*)&lds[32768 + o] = *(const short8v*)(Bh + gb);
            *(short8v*)&lds[49152 + o] = *(const short8v*)(Bl + gb);
        }
        __syncthreads();
        const int mr0 = (w >> 1) * 64, nc0 = (w & 1) * 64;
#pragma unroll
        for (int kk2 = 0; kk2 < 2; ++kk2) {
            const int kap = kk2 * 4 + (l >> 4);
            short8v ah[4], al[4], bh[4], bl[4];
#pragma unroll
            for (int i = 0; i < 4; ++i) {
                const int row = mr0 + i * 16 + (l & 15);
                const int off = row * 128 + ((kap ^ (row & 7)) * 16);
                ah[i] = *(const short8v*)&lds[off];
                al[i] = *(const short8v*)&lds[16384 + off];
            }
#pragma unroll
            for (int j = 0; j < 4; ++j) {
                const int bn = nc0 + j * 16 + (l & 15);
                const int off = bn * 128 + ((kap ^ (bn & 7)) * 16);
                bh[j] = *(const short8v*)&lds[32768 + off];
                bl[j] = *(const short8v*)&lds[49152 + off];
            }
#pragma unroll
            for (int i = 0; i < 4; ++i)
#pragma unroll
                for (int j = 0; j < 4; ++j) {
                    acc[i][j] = __builtin_amdgcn_mfma_f32_16x16x32_bf16(ah[i], bh[j], acc[i][j], 0, 0, 0);
                    acc[i][j] = __builtin_amdgcn_mfma_f32_16x16x32_bf16(ah[i], bl[j], acc[i][j], 0, 0, 0);
                    acc[i][j] = __builtin_amdgcn_mfma_f32_16x16x32_bf16(al[i], bh[j], acc[i][j], 0, 0, 0);
                }
        }
        __syncthreads();
    }
    const int mr0 = (w >> 1) * 64, nc0 = (w & 1) * 64;
#pragma unroll
    for (int j = 0; j < 4; ++j) {
        const int col = nb * 128 + nc0 + j * 16 + (l & 15);
        const float bv = bias[col];
#pragma unroll
        for (int i = 0; i < 4; ++i) {
            const int row0 = mb * 128 + mr0 + i * 16 + (l >> 4) * 4;
#pragma unroll
            for (int rg = 0; rg < 4; ++rg)
                C[(size_t)(row0 + rg) * 1536 + col] = acc[i][j][rg] + bv;
        }
    }
}

// ---- Phase 2 tile body: one GRU step for tile (rt, ct), 4 waves. ----
// Wave wv owns K-quarter [wv*128, wv*128+128) = 4 MFMA windows of 32.
// Fragments loaded DIRECTLY from global (no LDS staging): A fragment =
// h[row0+(l&15)][kw + (l>>4)*8] via 4 u64 agent-atomic loads + in-reg split;
// B fragment = pre-split bf16 w_hh b128 loads (L2-hot; same-ct blocks share
// an XCD since bid%8 == ct%8). Partials exchanged via 12KB LDS (scalar
// layout, static indices); wave wv reduces+stores row-group rg=wv in fixed
// order (deterministic).
__device__ __forceinline__ void gru_tile_body(
    float* accs_f,                             // LDS [4][3][4][64] floats
    const float* __restrict__ gi_s,            // [256,1536]
    const unsigned short* __restrict__ whhH,   // bf16 hi [1536,512]
    const unsigned short* __restrict__ whhL,   // bf16 lo
    const float* __restrict__ bhh,             // [1536]
    const float* __restrict__ hold,            // fp32 [256,512]
    float* __restrict__ hnew,                  // fp32 [256,512]
    const int tid, const int rt, const int ct)
{
    const int l = tid & 63, wv = tid >> 6;
    const int c0 = ct * 16, row0 = rt * 16;
    const int arow = l & 15;        // fragment row
    const int ksl  = l >> 4;        // k-slot within 32-k window
    const int kbase = wv * 128;     // this wave's K range

    // Issue all 4 windows' A loads upfront (the slow LLC ones).
    unsigned long long a_raw[4][4];
    const float* ha = hold + (size_t)(row0 + arow) * 512 + kbase + ksl * 8;
#pragma unroll
    for (int j = 0; j < 4; ++j)
#pragma unroll
        for (int q = 0; q < 4; ++q)
            a_raw[j][q] = h_load64(ha + j * 32 + q * 2);

    f32x4 acc[3] = {};
#pragma unroll
    for (int j = 0; j < 4; ++j) {
        QF buf;
#pragma unroll
        for (int q = 0; q < 4; ++q) buf.q[q] = a_raw[j][q];
        SV ah, al;
        split8(buf.v[0], buf.v[1], ah, al);
        const int ko = kbase + j * 32 + ksl * 8;
#pragma unroll
        for (int g = 0; g < 3; ++g) {
            const size_t wo = (size_t)((g << 9) + c0 + arow) * 512 + ko;
            const short8v bh = *(const short8v*)(whhH + wo);
            const short8v bl = *(const short8v*)(whhL + wo);
            acc[g] = __builtin_amdgcn_mfma_f32_16x16x32_bf16(ah.v, bh, acc[g], 0, 0, 0);
            acc[g] = __builtin_amdgcn_mfma_f32_16x16x32_bf16(ah.v, bl, acc[g], 0, 0, 0);
            acc[g] = __builtin_amdgcn_mfma_f32_16x16x32_bf16(al.v, bh, acc[g], 0, 0, 0);
        }
    }

    // Exchange partials: accs_f[wv][g][rg][lane]
#pragma unroll
    for (int g = 0; g < 3; ++g)
#pragma unroll
        for (int rg = 0; rg < 4; ++rg)
            accs_f[((wv * 3 + g) * 4 + rg) * 64 + l] = acc[g][rg];
    __syncthreads();

    // Wave wv handles rg = wv: rows row0 + (l>>4)*4 + wv, col c0 + (l&15).
    const int col = c0 + arow;
    const int row = row0 + ((l >> 4) << 2) + wv;
    float s0 = accs_f[((0 * 3 + 0) * 4 + wv) * 64 + l]
             + accs_f[((1 * 3 + 0) * 4 + wv) * 64 + l]
             + accs_f[((2 * 3 + 0) * 4 + wv) * 64 + l]
             + accs_f[((3 * 3 + 0) * 4 + wv) * 64 + l];
    float s1 = accs_f[((0 * 3 + 1) * 4 + wv) * 64 + l]
             + accs_f[((1 * 3 + 1) * 4 + wv) * 64 + l]
             + accs_f[((2 * 3 + 1) * 4 + wv) * 64 + l]
             + accs_f[((3 * 3 + 1) * 4 + wv) * 64 + l];
    float s2 = accs_f[((0 * 3 + 2) * 4 + wv) * 64 + l]
             + accs_f[((1 * 3 + 2) * 4 + wv) * 64 + l]
             + accs_f[((2 * 3 + 2) * 4 + wv) * 64 + l]
             + accs_f[((3 * 3 + 2) * 4 + wv) * 64 + l];
    const float* gp = gi_s + (size_t)row * 1536 + col;
    const float hv = h_load32(hold + (size_t)row * 512 + col);
    const float r = sigmoidf_(gp[0]    + s0 + bhh[col]);
    const float z = sigmoidf_(gp[512]  + s1 + bhh[512 + col]);
    const float n = tanhf(gp[1024] + r * (s2 + bhh[1024 + col]));
    h_store32(hnew + (size_t)row * 512 + col, (1.0f - z) * n + z * hv);
    __syncthreads();   // accs_f safe to overwrite next step
}

// ---- Phase 2a: cooperative persistent kernel — all tc steps, 1 launch. ----
// Grid 512 x 256 thr (4 waves; 2 blocks/CU -> 8 waves/CU, occupancy 25%).
__global__ __launch_bounds__(256, 2) void gru_coop(
    const float* __restrict__ gi,              // [tc,256,1536] chunk base
    const unsigned short* __restrict__ whhH,
    const unsigned short* __restrict__ whhL,
    const float* __restrict__ bhh,
    float* __restrict__ hA, float* __restrict__ hB,
    unsigned* __restrict__ flags,              // 16 groups x 32 u32
    const int t0, const int tc)
{
    __shared__ float accs_f[4 * 3 * 4 * 64];   // 12 KB
    const int tid = threadIdx.x;
    const int ct = blockIdx.x & 31;
    const int rt = blockIdx.x >> 5;
    unsigned* gf = flags + rt * 32;
    for (int s = 0; s < tc; ++s) {
        const int t = t0 + s;
        const float* hold = (t & 1) ? hB : hA;
        float* hnew = (t & 1) ? hA : hB;
        gru_tile_body(accs_f, gi + (size_t)s * 256 * 1536, whhH, whhL, bhh,
                      hold, hnew, tid, rt, ct);
        if (s + 1 < tc)
            group_barrier(gf, ct, (unsigned)(t + 1));
    }
}

// ---- Phase 2b: fallback — one step per launch (kernel boundary = barrier).
__global__ __launch_bounds__(256, 2) void gru_step_fb(
    const float* __restrict__ gi_s,
    const unsigned short* __restrict__ whhH,
    const unsigned short* __restrict__ whhL,
    const float* __restrict__ bhh,
    const float* __restrict__ hold, float* __restrict__ hnew)
{
    __shared__ float accs_f[4 * 3 * 4 * 64];
    gru_tile_body(accs_f, gi_s, whhH, whhL, bhh, hold, hnew,
                  threadIdx.x, blockIdx.x >> 5, blockIdx.x & 31);
}

// ---- Phase 3 fp32 GEMM (exact; known-good) ----
template<bool TANH>
__global__ __launch_bounds__(256) void gemm_nt_bias(
    const float* __restrict__ A, const float* __restrict__ B,
    const float* __restrict__ bias, float* __restrict__ C,
    const int N, const int K)
{
    __shared__ float As[32][68];
    __shared__ float Bs[32][68];
    const int nb = blockIdx.x, mb = blockIdx.y;
    const int t  = threadIdx.x;
    const int tx = t & 15, ty = t >> 4;
    const int lr = t >> 3;
    const int lk = (t & 7) << 2;
    const float* pA = A + (size_t)(mb * 64 + lr) * K + lk;
    const float* pB = B + (size_t)(nb * 64 + lr) * K + lk;
    float acc[4][4];
#pragma unroll
    for (int i = 0; i < 4; ++i)
#pragma unroll
        for (int j = 0; j < 4; ++j) acc[i][j] = 0.0f;
    for (int kk = 0; kk < K; kk += 32) {
        const float4 a0 = *(const float4*)(pA + kk);
        const float4 a1 = *(const float4*)(pA + (size_t)32 * K + kk);
        const float4 b0 = *(const float4*)(pB + kk);
        const float4 b1 = *(const float4*)(pB + (size_t)32 * K + kk);
        __syncthreads();
        As[lk+0][lr] = a0.x; As[lk+1][lr] = a0.y; As[lk+2][lr] = a0.z; As[lk+3][lr] = a0.w;
        As[lk+0][lr+32] = a1.x; As[lk+1][lr+32] = a1.y; As[lk+2][lr+32] = a1.z; As[lk+3][lr+32] = a1.w;
        Bs[lk+0][lr] = b0.x; Bs[lk+1][lr] = b0.y; Bs[lk+2][lr] = b0.z; Bs[lk+3][lr] = b0.w;
        Bs[lk+0][lr+32] = b1.x; Bs[lk+1][lr+32] = b1.y; Bs[lk+2][lr+32] = b1.z; Bs[lk+3][lr+32] = b1.w;
        __syncthreads();
#pragma unroll
        for (int k = 0; k < 32; ++k) {
            const float4 av = *(const float4*)&As[k][ty << 2];
            const float4 bv = *(const float4*)&Bs[k][tx << 2];
            acc[0][0] += av.x * bv.x; acc[0][1] += av.x * bv.y; acc[0][2] += av.x * bv.z; acc[0][3] += av.x * bv.w;
            acc[1][0] += av.y * bv.x; acc[1][1] += av.y * bv.y; acc[1][2] += av.y * bv.z; acc[1][3] += av.y * bv.w;
            acc[2][0] += av.z * bv.x; acc[2][1] += av.z * bv.y; acc[2][2] += av.z * bv.z; acc[2][3] += av.z * bv.w;
            acc[3][0] += av.w * bv.x; acc[3][1] += av.w * bv.y; acc[3][2] += av.w * bv.z; acc[3][3] += av.w * bv.w;
        }
    }
    const int crow = mb * 64 + (ty << 2);
    const int ccol = nb * 64 + (tx << 2);
    const float4 bv = *(const float4*)(bias + ccol);
#pragma unroll
    for (int i = 0; i < 4; ++i) {
        float4 o;
        o.x = acc[i][0] + bv.x; o.y = acc[i][1] + bv.y;
        o.z = acc[i][2] + bv.z; o.w = acc[i][3] + bv.w;
        if (TANH) { o.x = tanhf(o.x); o.y = tanhf(o.y); o.z = tanhf(o.z); o.w = tanhf(o.w); }
        *(float4*)(C + (size_t)(crow + i) * N + ccol) = o;
    }
}

__global__ __launch_bounds__(256) void value_head(
    const float* __restrict__ out1, const float* __restrict__ W2,
    const float* __restrict__ b2, float* __restrict__ out)
{
    const int b = blockIdx.x, t = threadIdx.x;
    float p = out1[(size_t)b * 512 + t] * W2[t]
            + out1[(size_t)b * 512 + 256 + t] * W2[256 + t];
#pragma unroll
    for (int off = 32; off > 0; off >>= 1) p += __shfl_down(p, off, 64);
    __shared__ float ps[4];
    if ((t & 63) == 0) ps[t >> 6] = p;
    __syncthreads();
    if (t == 0) out[b] = tanhf(ps[0] + ps[1] + ps[2] + ps[3] + b2[0]);
}

extern "C" void kernel_launch(void* const* d_in, const int* in_sizes, int n_in,
                              void* d_out, int out_size, void* d_ws, size_t ws_size,
                              hipStream_t stream)
{
    (void)in_sizes; (void)n_in; (void)out_size;
    const float* input = (const float*)d_in[0];   // [256,256,512]
    const float* w_ih  = (const float*)d_in[1];   // [1536,512]
    const float* w_hh  = (const float*)d_in[2];   // [1536,512]
    const float* b_ih  = (const float*)d_in[3];   // [1536]
    const float* b_hh  = (const float*)d_in[4];   // [1536]
    const float* W1    = (const float*)d_in[5];   // [512,512]
    const float* b1    = (const float*)d_in[6];   // [512]
    const float* W2    = (const float*)d_in[7];   // [512]
    const float* b2    = (const float*)d_in[8];   // [1]
    float* out = (float*)d_out;
    float* ws  = (float*)d_ws;

    // ws layout in FLOAT SLOTS. One [1536,512] bf16 buffer = 786432 ushorts
    // = 1,572,864 B = 393,216 float slots.
    float* hA = ws;                                        // [0, 131072)
    float* hB = ws + 131072;                               // [131072, 262144)
    float* o1 = ws + 262144;                               // [262144, 393216)
    unsigned short* wihH = (unsigned short*)(ws + 393216); // [393216, 786432)
    unsigned short* wihL = (unsigned short*)(ws + 786432); // [786432, 1179648)
    unsigned short* whhH = (unsigned short*)(ws + 1179648);// [1179648, 1572864)
    unsigned short* whhL = (unsigned short*)(ws + 1572864);// [1572864, 1966080)
    unsigned* flags = (unsigned*)(ws + 1966080);           // [1966080, 1966592) 512 u32
    float* gi = ws + 1966592;

    const size_t per_step = 256 * 1536;             // gi floats per timestep
    const size_t base = 1966592;
    const size_t avail = (ws_size / 4 > base) ? ws_size / 4 - base : 0;
    int Tc = (int)(avail / per_step);
    if (Tc > 256) Tc = 256;
    if (Tc < 1) Tc = 1;

    hipMemsetAsync(hA, 0, 131072 * sizeof(float), stream);    // h(-1) = 0
    hipMemsetAsync(flags, 0, 512 * sizeof(unsigned), stream); // barrier gen 0

    cast_split<<<768, 256, 0, stream>>>(w_ih, wihH, wihL, 196608);
    cast_split<<<768, 256, 0, stream>>>(w_hh, whhH, whhL, 196608);

    for (int t0 = 0; t0 < 256; t0 += Tc) {
        const int tc = (t0 + Tc <= 256) ? Tc : (256 - t0);
        const int Mc = tc * 256;
        // Phase 1 (chunk): gi = X_chunk @ w_ih^T + b_ih
        gemm_gi_mfma<<<dim3(12, Mc / 128), 256, 0, stream>>>(
            input + (size_t)t0 * 256 * 512, wihH, wihL, b_ih, gi);
        // Phase 2 (chunk): coop persistent kernel + per-group barrier.
        {
            const float* a_gi = gi;
            const unsigned short* a_wh = whhH; const unsigned short* a_wl = whhL;
            const float* a_bh = b_hh;
            float* a_hA = hA; float* a_hB = hB;
            unsigned* a_fl = flags;
            int a_t0 = t0; int a_tc = tc;
            void* args[] = {&a_gi, &a_wh, &a_wl, &a_bh, &a_hA, &a_hB, &a_fl, &a_t0, &a_tc};
            hipError_t rc = hipLaunchCooperativeKernel(
                (const void*)gru_coop, dim3(512), dim3(256), args, 0, stream);
            if (rc != hipSuccess) {
                // Fallback: per-step launches (kernel boundary = grid barrier)
                for (int s = 0; s < tc; ++s) {
                    const int t = t0 + s;
                    const float* hold = (t & 1) ? hB : hA;
                    float* hnew = (t & 1) ? hA : hB;
                    gru_step_fb<<<dim3(512), 256, 0, stream>>>(
                        gi + (size_t)s * per_step, whhH, whhL, b_hh, hold, hnew);
                }
            }
        }
    }

    // Phase 3: final h is in hA (after 256 steps, even count).
    gemm_nt_bias<true><<<dim3(512 / 64, 256 / 64), 256, 0, stream>>>(
        hA, W1, b1, o1, 512, 512);
    value_head<<<256, 256, 0, stream>>>(o1, W2, b2, out);
}